// Round 4
// baseline (1243.901 us; speedup 1.0000x reference)
//
#include <hip/hip_runtime.h>
#include <cstdio>

#define BB 4
#define C 64
#define HH 192
#define WW 192
#define NPIX (HH*WW)            /* 36864 */
#define ST (BB*C*NPIX)          /* 9437184 floats per tensor */

__device__ __forceinline__ float gelu_f(float v) {
    return 0.5f * v * (1.0f + erff(v * 0.70710678118654752440f));
}

// ---------------------------------------------------------------------------
// Generic 1x1 conv over NCHW: out[b,o,n] = W1@in1 (+ W2@in2) (+bias1)(+bias2)
// (+res)(gelu). grid = (NPIX/256, B), block = 256. out1 never aliases inputs.
// ---------------------------------------------------------------------------
template<bool TWO_IN, bool PERB, bool DO_GELU>
__global__ __launch_bounds__(256) void k_conv(
    const float* __restrict__ in1, const float* __restrict__ in2,
    const float* __restrict__ W1, const float* __restrict__ W2,
    const float* __restrict__ bias1, const float* __restrict__ bias2,
    const float* __restrict__ res, float* __restrict__ out1,
    int ldw1, int ldw2)
{
    const int n = blockIdx.x * 256 + threadIdx.x;
    const int b = blockIdx.y;
    const int base = b * (C * NPIX) + n;
    float xv[C];
#pragma unroll
    for (int c = 0; c < C; ++c) xv[c] = in1[base + c * NPIX];
    float yv[TWO_IN ? C : 1];
    if (TWO_IN) {
#pragma unroll
        for (int c = 0; c < C; ++c) yv[c] = in2[base + c * NPIX];
    }
    const float* w1 = W1 + (PERB ? b * C * C : 0);
    for (int o = 0; o < C; ++o) {
        const float* wr = w1 + o * ldw1;
        float a0 = 0.f, a1 = 0.f, a2 = 0.f, a3 = 0.f;
#pragma unroll
        for (int c = 0; c < C; c += 4) {
            a0 += wr[c+0] * xv[c+0];
            a1 += wr[c+1] * xv[c+1];
            a2 += wr[c+2] * xv[c+2];
            a3 += wr[c+3] * xv[c+3];
        }
        if (TWO_IN) {
            const float* wr2 = W2 + o * ldw2;
#pragma unroll
            for (int c = 0; c < C; c += 4) {
                a0 += wr2[c+0] * yv[c+0];
                a1 += wr2[c+1] * yv[c+1];
                a2 += wr2[c+2] * yv[c+2];
                a3 += wr2[c+3] * yv[c+3];
            }
        }
        float acc = (a0 + a1) + (a2 + a3);
        if (bias1) acc += bias1[o];
        if (bias2) acc += bias2[o];
        const int ob = base + o * NPIX;
        if (res) acc += res[ob];
        if (DO_GELU) acc = gelu_f(acc);
        out1[ob] = acc;
    }
}

// ---------------------------------------------------------------------------
// Depthwise 3x3 (pad 1) + bias + GELU.  grid = (H, B*C), block = 192 (=W).
// ---------------------------------------------------------------------------
__global__ __launch_bounds__(192) void k_dw(
    const float* __restrict__ t0, const float* __restrict__ w,
    const float* __restrict__ bias, float* __restrict__ g)
{
    const int x = threadIdx.x;
    const int y = blockIdx.x;
    const int bc = blockIdx.y;
    const int c = bc & 63;
    const float* img = t0 + bc * NPIX;
    const float* wc = w + c * 9;
    float acc = bias[c];
#pragma unroll
    for (int dy = -1; dy <= 1; ++dy) {
        const int yy = y + dy;
        if (yy < 0 || yy > 191) continue;
#pragma unroll
        for (int dx = -1; dx <= 1; ++dx) {
            const int xx = x + dx;
            if (xx < 0 || xx > 191) continue;
            acc += img[yy*WW + xx] * wc[(dy+1)*3 + (dx+1)];
        }
    }
    g[bc*NPIX + y*WW + x] = gelu_f(acc);
}

// ---------------------------------------------------------------------------
// Per-batch Gram G1 = X1 * X1^T: partial per 256-pixel chunk.
// ---------------------------------------------------------------------------
__global__ __launch_bounds__(256) void k_gram_part(
    const float* __restrict__ x1p, float* __restrict__ part)
{
    extern __shared__ float lt[];     // [256][68]
    const int chunk = blockIdx.x, b = blockIdx.y, t = threadIdx.x;
    const int gbase = b * (C*NPIX) + chunk * 256;
    for (int idx = t; idx < C*256; idx += 256) {
        const int c = idx >> 8, n = idx & 255;
        lt[n*68 + c] = x1p[gbase + c*NPIX + n];
    }
    __syncthreads();
    const int ti = t & 15, tj = t >> 4;
    float acc[4][4];
#pragma unroll
    for (int r = 0; r < 4; ++r)
#pragma unroll
        for (int s = 0; s < 4; ++s) acc[r][s] = 0.f;
    for (int n = 0; n < 256; ++n) {
        const float4 av = *reinterpret_cast<const float4*>(&lt[n*68 + 4*ti]);
        const float4 bv = *reinterpret_cast<const float4*>(&lt[n*68 + 4*tj]);
        const float ar[4] = {av.x, av.y, av.z, av.w};
        const float br[4] = {bv.x, bv.y, bv.z, bv.w};
#pragma unroll
        for (int r = 0; r < 4; ++r)
#pragma unroll
            for (int s = 0; s < 4; ++s) acc[r][s] += ar[r] * br[s];
    }
    float* pb = part + (b*144 + chunk)*4096;
#pragma unroll
    for (int r = 0; r < 4; ++r)
#pragma unroll
        for (int s = 0; s < 4; ++s) pb[(4*ti+r)*64 + (4*tj+s)] = acc[r][s];
}

__global__ __launch_bounds__(256) void k_gram_reduce(
    const float* __restrict__ part, float* __restrict__ G1)
{
    const int flat = blockIdx.x*256 + threadIdx.x;   // < 16384
    const int b = flat >> 12, ij = flat & 4095;
    float s = 0.f;
    for (int ch = 0; ch < 144; ++ch) s += part[(b*144+ch)*4096 + ij];
    G1[flat] = s;
}

// ---------------------------------------------------------------------------
// Channel-attention collapse: per batch, M2 = Wp * blockdiag(attn) * Wv.
// ---------------------------------------------------------------------------
__global__ __launch_bounds__(256) void k_attn_small(
    const float* __restrict__ G1a, const float* __restrict__ Wq,
    const float* __restrict__ Wk, const float* __restrict__ Wv,
    const float* __restrict__ Wp, const float* __restrict__ temp,
    float* __restrict__ M2)
{
    extern __shared__ float sm[];
    float* g1 = sm;
    float* wa = sm + 4096;
    float* wb = sm + 8192;
    float* u  = sm + 12288;
    float* at = sm + 16384;
    float* nq = sm + 18432;
    float* nk = sm + 18496;
    const int b = blockIdx.x, t = threadIdx.x;
    const float* G = G1a + b*4096;
    for (int i = t; i < 4096; i += 256) { g1[i] = G[i]; wa[i] = Wq[i]; wb[i] = Wk[i]; }
    __syncthreads();
    {
        const int r = t >> 2, q4 = t & 3;
        for (int cc = q4*16; cc < q4*16 + 16; ++cc) {
            float s = 0.f;
            for (int k = 0; k < 64; ++k) s += wa[r*64+k] * g1[k*64+cc];
            u[r*64+cc] = s;
        }
    }
    __syncthreads();
    {
        const int d = t >> 2, kq = t & 3;
        float p = 0.f;
        for (int k = kq*16; k < kq*16 + 16; ++k) {
            float tk = 0.f;
            for (int c2 = 0; c2 < 64; ++c2) tk += g1[k*64+c2] * wb[d*64+c2];
            p += wb[d*64+k] * tk;
        }
        p += __shfl_xor(p, 1);
        p += __shfl_xor(p, 2);
        if (kq == 0) nk[d] = sqrtf(fmaxf(p, 0.f));
    }
    if (t < 64) {
        float s = 0.f;
        for (int c2 = 0; c2 < 64; ++c2) s += u[t*64+c2] * wa[t*64+c2];
        nq[t] = sqrtf(fmaxf(s, 0.f));
    }
    __syncthreads();
    if (t < 64) {
        const int gI = t >> 5;
        const float tg = temp[gI];
        const float dq = fmaxf(nq[t], 1e-12f);
        float row[32];
        float mx = -1e30f;
#pragma unroll
        for (int d2 = 0; d2 < 32; ++d2) {
            const int dd = gI*32 + d2;
            float s = 0.f;
            for (int c2 = 0; c2 < 64; ++c2) s += u[t*64+c2] * wb[dd*64+c2];
            s = s * tg / (dq * fmaxf(nk[dd], 1e-12f));
            row[d2] = s; mx = fmaxf(mx, s);
        }
        float se = 0.f;
#pragma unroll
        for (int d2 = 0; d2 < 32; ++d2) { row[d2] = __expf(row[d2]-mx); se += row[d2]; }
        const float inv = 1.f / se;
#pragma unroll
        for (int d2 = 0; d2 < 32; ++d2) at[t*32+d2] = row[d2]*inv;
    }
    __syncthreads();
    for (int i = t; i < 4096; i += 256) { wa[i] = Wv[i]; wb[i] = Wp[i]; }
    __syncthreads();
    {
        const int m = t >> 2, q4 = t & 3, gI = m >> 5;
        for (int e = q4*16; e < q4*16 + 16; ++e) {
            float s = 0.f;
#pragma unroll
            for (int d2 = 0; d2 < 32; ++d2) s += at[m*32+d2] * wa[(gI*32+d2)*64 + e];
            g1[m*64+e] = s;
        }
    }
    __syncthreads();
    {
        const int o = t >> 2, q4 = t & 3;
        for (int e = q4*16; e < q4*16 + 16; ++e) {
            float s = 0.f;
            for (int m = 0; m < 64; ++m) s += wb[o*64+m] * g1[m*64+e];
            M2[b*4096 + o*64+e] = s;
        }
    }
}

// ---------------------------------------------------------------------------
// Small weight-folding products:
//  0: Wtr = rq^T rk   1: Wtc = cq^T ck
//  2: Wf2p = gr * Wf[:,64:128] @ rv   3: Wf3p = gc * Wf[:,128:192] @ cv
//  4: Wfx  = Wf[:,64:128] + Wf[:,128:192]
// ---------------------------------------------------------------------------
__global__ __launch_bounds__(256) void k_small_mats(
    const float* __restrict__ rq, const float* __restrict__ rk,
    const float* __restrict__ cq, const float* __restrict__ ck,
    const float* __restrict__ fw, const float* __restrict__ rv,
    const float* __restrict__ cv, const float* __restrict__ rg,
    const float* __restrict__ cg,
    float* __restrict__ Wtr, float* __restrict__ Wtc,
    float* __restrict__ Wf2p, float* __restrict__ Wf3p,
    float* __restrict__ Wfx)
{
    const int which = blockIdx.x, t = threadIdx.x;
    const int a = t >> 2, b0 = (t & 3) * 16;
    if (which <= 1) {
        const float* Q = which ? cq : rq;
        const float* Kw = which ? ck : rk;
        float* O = which ? Wtc : Wtr;
        for (int b = b0; b < b0 + 16; ++b) {
            float s = 0.f;
            for (int co = 0; co < 64; ++co) s += Q[co*64 + a] * Kw[co*64 + b];
            O[a*64 + b] = s;
        }
    } else if (which <= 3) {
        const float* Vw = (which == 2) ? rv : cv;
        const float g = (which == 2) ? rg[0] : cg[0];
        const int off = (which == 2) ? 64 : 128;
        float* O = (which == 2) ? Wf2p : Wf3p;
        for (int b = b0; b < b0 + 16; ++b) {
            float s = 0.f;
            for (int m = 0; m < 64; ++m) s += fw[a*192 + off + m] * Vw[m*64 + b];
            O[a*64 + b] = g * s;
        }
    } else {
        for (int b = b0; b < b0 + 16; ++b)
            Wfx[a*64 + b] = fw[a*192 + 64 + b] + fw[a*192 + 128 + b];
    }
}

// ---------------------------------------------------------------------------
// FUSED per-line attention, HALF-LINE blocks (2 blocks per (h,b) line).
// Factorization: S = (X^T Wt) X. Each block owns IH=96 S-rows:
//   Q[i'][c2] = sum_a X[a][ih0+i'] Wt[a][c2]   (Wt read from global, L2-hot)
//   S[i'][j]  = sum_c2 Q[i'][c2] X[c2][j]
//   P = softmax_rows(S)  (rows independent -> halves independent)
//   Z[c][ih0+i'] = sum_j U[c][j] P[i'][j]
// grid (192, 2*B): by&1 = half, by>>1 = batch. block = 256.
// LDS (floats): phase A: Xl[64][196]@0 (12544) + Ql[64][98]@12544 (6272)
//               phase B: Pl[96][196]@0 (18816, overlays Xl+Ql exactly),
//                        Ut[16][68]@18816 (1088, U transposed, 16-wide jt)
// dyn LDS = 19904*4 = 79616 B -> 2 blocks/CU -> 8 waves/CU (2/SIMD).
// Z stores stay float4 (16B) -- 8B stores double WRITE_SIZE (R1 evidence).
// ---------------------------------------------------------------------------
#define SP 196
#define QSTR 98
#define UTS 68
#define IH 96
__global__ __launch_bounds__(256, 2) void k_attn_fused(
    const float* __restrict__ X, const float* __restrict__ Wt,
    const float* __restrict__ U, float* __restrict__ Z)
{
    extern __shared__ float sm[];
    float* Xl = sm;                    // [64][196]
    float* Ql = sm + 12544;            // [64][98]   Ql[c2][i']
    float* Pl = sm;                    // [96][196]  overlay (phase B)
    float* Ut = sm + 18816;            // [16][68]   Ut[j'][c] (phase B)
    float* red  = sm;                  // [96][17]   softmax scratch overlay
    float* mrow = sm + 96*17;          // 96
    float* lrow = sm + 96*17 + 96;     // 96
    const int t = threadIdx.x;
    const int h = blockIdx.x;
    const int half = blockIdx.y & 1, b = blockIdx.y >> 1;
    const int ih0 = half * IH;
    const size_t gbase = (size_t)b*(C*NPIX) + (size_t)h*WW;

    // --- phase 0: load X line ---
#pragma unroll 4
    for (int k = 0; k < 48; ++k) {
        const int idx = k*256 + t;
        const int c = idx / 192, j = idx - c*192;
        Xl[c*SP + j] = X[gbase + (size_t)c*NPIX + j];
    }
    __syncthreads();

    // --- phase Q: Ql[c2][i'] = sum_a Xl[a][ih0+i'] * Wt[a][c2] ---
    {
        const int qc2 = t & 15, qi = t >> 4;       // c2-tile 4, i-tile 6
        const int c20 = 4*qc2, iq0 = ih0 + 6*qi;
        float accq[4][6];
#pragma unroll
        for (int k = 0; k < 4; ++k)
#pragma unroll
            for (int m = 0; m < 6; ++m) accq[k][m] = 0.f;
#pragma unroll 4
        for (int a = 0; a < 64; ++a) {
            const float4 w4 = *reinterpret_cast<const float4*>(&Wt[a*64 + c20]);
            const float2 xa = *reinterpret_cast<const float2*>(&Xl[a*SP + iq0]);
            const float2 xb = *reinterpret_cast<const float2*>(&Xl[a*SP + iq0 + 2]);
            const float2 xc = *reinterpret_cast<const float2*>(&Xl[a*SP + iq0 + 4]);
            const float wr[4] = {w4.x, w4.y, w4.z, w4.w};
            const float xr[6] = {xa.x, xa.y, xb.x, xb.y, xc.x, xc.y};
#pragma unroll
            for (int k = 0; k < 4; ++k)
#pragma unroll
                for (int m = 0; m < 6; ++m) accq[k][m] += wr[k] * xr[m];
        }
#pragma unroll
        for (int k = 0; k < 4; ++k) {
            float* qr = &Ql[(c20+k)*QSTR + 6*qi];
            float2 o0, o1, o2;
            o0.x = accq[k][0]; o0.y = accq[k][1];
            o1.x = accq[k][2]; o1.y = accq[k][3];
            o2.x = accq[k][4]; o2.y = accq[k][5];
            *reinterpret_cast<float2*>(qr)     = o0;
            *reinterpret_cast<float2*>(qr + 2) = o1;
            *reinterpret_cast<float2*>(qr + 4) = o2;
        }
    }
    __syncthreads();

    // --- phase S: S[i'][j] = sum_c2 Ql[c2][i'] Xl[c2][j], 6x12/thread ---
    const int ti = t & 15, tj = t >> 4;
    const int i0 = ti*6, j0 = tj*12;
    float acc[6][12];
#pragma unroll
    for (int r = 0; r < 6; ++r)
#pragma unroll
        for (int s = 0; s < 12; ++s) acc[r][s] = 0.f;
#pragma unroll 2
    for (int c2 = 0; c2 < 64; ++c2) {
        const float2 qa = *reinterpret_cast<const float2*>(&Ql[c2*QSTR + i0]);
        const float2 qb = *reinterpret_cast<const float2*>(&Ql[c2*QSTR + i0 + 2]);
        const float2 qc = *reinterpret_cast<const float2*>(&Ql[c2*QSTR + i0 + 4]);
        const float4 ya = *reinterpret_cast<const float4*>(&Xl[c2*SP + j0]);
        const float4 yb = *reinterpret_cast<const float4*>(&Xl[c2*SP + j0 + 4]);
        const float4 yc = *reinterpret_cast<const float4*>(&Xl[c2*SP + j0 + 8]);
        const float xr[6]  = {qa.x,qa.y, qb.x,qb.y, qc.x,qc.y};
        const float yr[12] = {ya.x,ya.y,ya.z,ya.w, yb.x,yb.y,yb.z,yb.w,
                              yc.x,yc.y,yc.z,yc.w};
#pragma unroll
        for (int r = 0; r < 6; ++r)
#pragma unroll
            for (int s = 0; s < 12; ++s) acc[r][s] += xr[r] * yr[s];
    }
    __syncthreads();   // Xl/Ql dead; red overlays

    // --- softmax over rows (96 local rows) ---
#pragma unroll
    for (int r = 0; r < 6; ++r) {
        float pm = acc[r][0];
#pragma unroll
        for (int s = 1; s < 12; ++s) pm = fmaxf(pm, acc[r][s]);
        red[(i0 + r)*17 + tj] = pm;
    }
    __syncthreads();
    if (t < IH) {
        float m = red[t*17];
#pragma unroll
        for (int k = 1; k < 16; ++k) m = fmaxf(m, red[t*17 + k]);
        mrow[t] = m;
    }
    __syncthreads();
#pragma unroll
    for (int r = 0; r < 6; ++r) {
        const float mi = mrow[i0 + r];
        float ps = 0.f;
#pragma unroll
        for (int s = 0; s < 12; ++s) {
            acc[r][s] = __expf(acc[r][s] - mi);
            ps += acc[r][s];
        }
        red[(i0 + r)*17 + tj] = ps;
    }
    __syncthreads();
    if (t < IH) {
        float l = 0.f;
#pragma unroll
        for (int k = 0; k < 16; ++k) l += red[t*17 + k];
        lrow[t] = 1.f / l;
    }
    __syncthreads();
    float invl[6];
#pragma unroll
    for (int r = 0; r < 6; ++r) invl[r] = lrow[i0 + r];
    __syncthreads();   // scratch reads done; Pl may overwrite

    // --- store normalized P into LDS ---
#pragma unroll
    for (int r = 0; r < 6; ++r) {
        const float inv = invl[r];
        float4 o0, o1, o2;
        o0.x = acc[r][0]*inv;  o0.y = acc[r][1]*inv;  o0.z = acc[r][2]*inv;  o0.w = acc[r][3]*inv;
        o1.x = acc[r][4]*inv;  o1.y = acc[r][5]*inv;  o1.z = acc[r][6]*inv;  o1.w = acc[r][7]*inv;
        o2.x = acc[r][8]*inv;  o2.y = acc[r][9]*inv;  o2.z = acc[r][10]*inv; o2.w = acc[r][11]*inv;
        float* pr = &Pl[(i0 + r)*SP + j0];
        *reinterpret_cast<float4*>(pr)     = o0;
        *reinterpret_cast<float4*>(pr + 4) = o1;
        *reinterpret_cast<float4*>(pr + 8) = o2;
    }

    // T14 prologue: first U tile (jt=0) into regs before the barrier
    const int uj = t & 15;             // j' within 16-tile
    const int uc0 = t >> 4;            // c sub-index (0..15)
    float rU[4];
#pragma unroll
    for (int kk = 0; kk < 4; ++kk)
        rU[kk] = U[gbase + (size_t)(uc0 + 16*kk)*NPIX + uj];
    __syncthreads();

    // --- phase 5: Z[c][ih0+i'] = sum_j U[c][j] P[i'][j], jt tiles of 16 ---
    const int ci = t & 31, ii = t >> 5;            // 2 c-rows, 12 i-cols
    const int c0z = 2*ci, i0z = 12*ii;
    float accz[2][12];
#pragma unroll
    for (int k = 0; k < 2; ++k)
#pragma unroll
        for (int m = 0; m < 12; ++m) accz[k][m] = 0.f;
    for (int jt = 0; jt < 192; jt += 16) {
        // write staged regs -> Ut[j'][c]
#pragma unroll
        for (int kk = 0; kk < 4; ++kk)
            Ut[uj*UTS + uc0 + 16*kk] = rU[kk];
        __syncthreads();
        // prefetch next tile into regs; latency hides under jq compute
        if (jt + 16 < 192) {
#pragma unroll
            for (int kk = 0; kk < 4; ++kk)
                rU[kk] = U[gbase + (size_t)(uc0 + 16*kk)*NPIX + jt + 16 + uj];
        }
#pragma unroll
        for (int jq = 0; jq < 4; ++jq) {
            const float2 uq0 = *reinterpret_cast<const float2*>(&Ut[(4*jq+0)*UTS + c0z]);
            const float2 uq1 = *reinterpret_cast<const float2*>(&Ut[(4*jq+1)*UTS + c0z]);
            const float2 uq2 = *reinterpret_cast<const float2*>(&Ut[(4*jq+2)*UTS + c0z]);
            const float2 uq3 = *reinterpret_cast<const float2*>(&Ut[(4*jq+3)*UTS + c0z]);
            const float u0[2] = {uq0.x, uq0.y};
            const float u1[2] = {uq1.x, uq1.y};
            const float u2[2] = {uq2.x, uq2.y};
            const float u3[2] = {uq3.x, uq3.y};
            float4 p4[12];
#pragma unroll
            for (int m = 0; m < 12; ++m)
                p4[m] = *reinterpret_cast<const float4*>(&Pl[(i0z+m)*SP + jt + 4*jq]);
#pragma unroll
            for (int k = 0; k < 2; ++k)
#pragma unroll
                for (int m = 0; m < 12; ++m) {
                    accz[k][m] += u0[k]*p4[m].x + u1[k]*p4[m].y
                                + u2[k]*p4[m].z + u3[k]*p4[m].w;
                }
        }
        __syncthreads();
    }
#pragma unroll
    for (int k = 0; k < 2; ++k) {
        float* zr = Z + gbase + (size_t)(c0z + k)*NPIX + ih0 + i0z;
        float4 o0, o1, o2;
        o0.x = accz[k][0]; o0.y = accz[k][1]; o0.z = accz[k][2];  o0.w = accz[k][3];
        o1.x = accz[k][4]; o1.y = accz[k][5]; o1.z = accz[k][6];  o1.w = accz[k][7];
        o2.x = accz[k][8]; o2.y = accz[k][9]; o2.z = accz[k][10]; o2.w = accz[k][11];
        *reinterpret_cast<float4*>(zr)     = o0;
        *reinterpret_cast<float4*>(zr + 4) = o1;
        *reinterpret_cast<float4*>(zr + 8) = o2;
    }
}

// ---------------------------------------------------------------------------
// HW transpose per image: out[img][x][y] = in[img][y][x]. grid (6,6,B*C).
// ---------------------------------------------------------------------------
__global__ __launch_bounds__(256) void k_transpose(
    const float* __restrict__ in, float* __restrict__ out)
{
    __shared__ float tile[32][33];
    const int tx = threadIdx.x & 31, ty = threadIdx.x >> 5;
    const int x0 = blockIdx.x*32, y0 = blockIdx.y*32;
    const float* img = in + blockIdx.z * NPIX;
    float* og = out + blockIdx.z * NPIX;
#pragma unroll
    for (int r = ty; r < 32; r += 8) tile[r][tx] = img[(y0+r)*WW + x0+tx];
    __syncthreads();
#pragma unroll
    for (int r = ty; r < 32; r += 8) og[(x0+r)*WW + (y0+tx)] = tile[tx][r];
}

// ---------------------------------------------------------------------------
extern "C" void kernel_launch(void* const* d_in, const int* in_sizes, int n_in,
                              void* d_out, int out_size, void* d_ws, size_t ws_size,
                              hipStream_t stream) {
    const float* x       = (const float*)d_in[0];
    const float* pw_w    = (const float*)d_in[1];
    const float* dw_w    = (const float*)d_in[2];
    const float* dw_b    = (const float*)d_in[3];
    const float* conv2_w = (const float*)d_in[4];
    const float* conv2_b = (const float*)d_in[5];
    const float* conv0_w = (const float*)d_in[6];
    const float* conv0_b = (const float*)d_in[7];
    const float* attq    = (const float*)d_in[8];
    const float* attk    = (const float*)d_in[9];
    const float* attv    = (const float*)d_in[10];
    const float* attp    = (const float*)d_in[11];
    const float* temp    = (const float*)d_in[12];
    const float* rq      = (const float*)d_in[13];
    const float* rk      = (const float*)d_in[14];
    const float* rv      = (const float*)d_in[15];
    const float* rg      = (const float*)d_in[16];
    const float* cq      = (const float*)d_in[17];
    const float* ck      = (const float*)d_in[18];
    const float* cv      = (const float*)d_in[19];
    const float* cg      = (const float*)d_in[20];
    const float* fw      = (const float*)d_in[21];
    const float* fb      = (const float*)d_in[22];

    float* ws = (float*)d_ws;
    float* A  = ws;                 // t0 -> x1 (lives to end)
    float* Bf = ws + (size_t)ST;    // g -> out1
    float* Cf = ws + 2*(size_t)ST;  // x1t -> Z2
    float* Df = ws + 3*(size_t)ST;  // out1t -> Z3
    float* Ef = ws + 4*(size_t)ST;  // Z3t -> final pass-1 tmp
    float* partials = ws + 5*(size_t)ST;   // 576*4096 = 2359296 floats
    float* G1 = partials + 576*4096;       // 16384
    float* M2 = G1 + 16384;                // 16384
    float* Wtr  = M2 + 16384;              // 5 x 4096
    float* Wtc  = Wtr + 4096;
    float* Wf2p = Wtc + 4096;
    float* Wf3p = Wf2p + 4096;
    float* Wfx  = Wf3p + 4096;

    const size_t need = ((size_t)5*ST + 576*4096 + 16384 + 16384 + 5*4096)
                        * sizeof(float);
    if (ws_size < need) {
        fprintf(stderr, "kernel_launch: ws_size %zu < needed %zu\n", ws_size, need);
        return;
    }

    (void)hipFuncSetAttribute((const void*)k_gram_part,
        hipFuncAttributeMaxDynamicSharedMemorySize, 69632);
    (void)hipFuncSetAttribute((const void*)k_attn_small,
        hipFuncAttributeMaxDynamicSharedMemorySize, 74240);
    (void)hipFuncSetAttribute((const void*)k_attn_fused,
        hipFuncAttributeMaxDynamicSharedMemorySize, 79616);

    const dim3 blk256(256), blk192(192);
    const dim3 gconv(NPIX/256, BB);      // (144, 4)
    const dim3 gline(HH, 2*BB);          // (192, 8): half-line blocks
    const dim3 gtr(6, 6, BB*C);

    // 0) fold weights
    k_small_mats<<<dim3(5), blk256, 0, stream>>>(rq, rk, cq, ck, fw, rv, cv,
                                                 rg, cg, Wtr, Wtc, Wf2p, Wf3p, Wfx);
    // 1) A = pw_w @ x
    k_conv<false,false,false><<<gconv, blk256, 0, stream>>>(
        x, nullptr, pw_w, nullptr, nullptr, nullptr, nullptr, A, 64, 64);
    // 2) B = gelu(dw3x3(A) + dw_b)
    k_dw<<<dim3(HH, BB*C), blk192, 0, stream>>>(A, dw_w, dw_b, Bf);
    // 3) A = x1 = conv2@B + conv0@x + conv2_b + conv0_b
    k_conv<true,false,false><<<gconv, blk256, 0, stream>>>(
        Bf, x, conv2_w, conv0_w, conv2_b, conv0_b, nullptr, A, 64, 64);
    // 4) channel attention collapse -> M2
    k_gram_part<<<gconv, blk256, 69632, stream>>>(A, partials);
    k_gram_reduce<<<dim3(64), blk256, 0, stream>>>(partials, G1);
    k_attn_small<<<dim3(BB), blk256, 74240, stream>>>(G1, attq, attk, attv, attp, temp, M2);
    // 5) B = out1 = M2[b] @ x1
    k_conv<false,true,false><<<gconv, blk256, 0, stream>>>(
        A, nullptr, M2, nullptr, nullptr, nullptr, nullptr, Bf, 64, 64);
    // 6) C = x1t, D = out1t
    k_transpose<<<gtr, blk256, 0, stream>>>(A, Cf);
    k_transpose<<<gtr, blk256, 0, stream>>>(Bf, Df);
    // 7) col attention fused: E = Z3t
    k_attn_fused<<<gline, blk256, 79616, stream>>>(Cf, Wtc, Df, Ef);
    // 8) D = Z3 = transpose(Z3t)
    k_transpose<<<gtr, blk256, 0, stream>>>(Ef, Df);
    // 9) row attention fused: C = Z2
    k_attn_fused<<<gline, blk256, 79616, stream>>>(A, Wtr, Bf, Cf);
    // 10) final fuse (folded): out = gelu(Wf1@out1 + Wf2p@Z2 + Wf3p@Z3
    //                                      + Wfx@x1 + fb)
    k_conv<true,false,false><<<gconv, blk256, 0, stream>>>(
        Bf, Cf, fw, Wf2p, fb, nullptr, nullptr, Ef, 192, 64);
    k_conv<true,false,true><<<gconv, blk256, 0, stream>>>(
        Df, A, Wf3p, Wfx, nullptr, nullptr, Ef, (float*)d_out, 64, 64);
}

// Round 5
// 1154.876 us; speedup vs baseline: 1.0771x; 1.0771x over previous
//
#include <hip/hip_runtime.h>
#include <cstdio>

#define BB 4
#define C 64
#define HH 192
#define WW 192
#define NPIX (HH*WW)            /* 36864 */
#define ST (BB*C*NPIX)          /* 9437184 floats per tensor */

__device__ __forceinline__ float gelu_f(float v) {
    return 0.5f * v * (1.0f + erff(v * 0.70710678118654752440f));
}

// ---------------------------------------------------------------------------
// Generic 1x1 conv over NCHW: out[b,o,n] = W1@in1 (+ W2@in2) (+bias1)(+bias2)
// (+res)(gelu). grid = (NPIX/256, B), block = 256. out1 never aliases inputs.
// ---------------------------------------------------------------------------
template<bool TWO_IN, bool PERB, bool DO_GELU>
__global__ __launch_bounds__(256) void k_conv(
    const float* __restrict__ in1, const float* __restrict__ in2,
    const float* __restrict__ W1, const float* __restrict__ W2,
    const float* __restrict__ bias1, const float* __restrict__ bias2,
    const float* __restrict__ res, float* __restrict__ out1,
    int ldw1, int ldw2)
{
    const int n = blockIdx.x * 256 + threadIdx.x;
    const int b = blockIdx.y;
    const int base = b * (C * NPIX) + n;
    float xv[C];
#pragma unroll
    for (int c = 0; c < C; ++c) xv[c] = in1[base + c * NPIX];
    float yv[TWO_IN ? C : 1];
    if (TWO_IN) {
#pragma unroll
        for (int c = 0; c < C; ++c) yv[c] = in2[base + c * NPIX];
    }
    const float* w1 = W1 + (PERB ? b * C * C : 0);
    for (int o = 0; o < C; ++o) {
        const float* wr = w1 + o * ldw1;
        float a0 = 0.f, a1 = 0.f, a2 = 0.f, a3 = 0.f;
#pragma unroll
        for (int c = 0; c < C; c += 4) {
            a0 += wr[c+0] * xv[c+0];
            a1 += wr[c+1] * xv[c+1];
            a2 += wr[c+2] * xv[c+2];
            a3 += wr[c+3] * xv[c+3];
        }
        if (TWO_IN) {
            const float* wr2 = W2 + o * ldw2;
#pragma unroll
            for (int c = 0; c < C; c += 4) {
                a0 += wr2[c+0] * yv[c+0];
                a1 += wr2[c+1] * yv[c+1];
                a2 += wr2[c+2] * yv[c+2];
                a3 += wr2[c+3] * yv[c+3];
            }
        }
        float acc = (a0 + a1) + (a2 + a3);
        if (bias1) acc += bias1[o];
        if (bias2) acc += bias2[o];
        const int ob = base + o * NPIX;
        if (res) acc += res[ob];
        if (DO_GELU) acc = gelu_f(acc);
        out1[ob] = acc;
    }
}

// ---------------------------------------------------------------------------
// Depthwise 3x3 (pad 1) + bias + GELU.  grid = (H, B*C), block = 192 (=W).
// ---------------------------------------------------------------------------
__global__ __launch_bounds__(192) void k_dw(
    const float* __restrict__ t0, const float* __restrict__ w,
    const float* __restrict__ bias, float* __restrict__ g)
{
    const int x = threadIdx.x;
    const int y = blockIdx.x;
    const int bc = blockIdx.y;
    const int c = bc & 63;
    const float* img = t0 + bc * NPIX;
    const float* wc = w + c * 9;
    float acc = bias[c];
#pragma unroll
    for (int dy = -1; dy <= 1; ++dy) {
        const int yy = y + dy;
        if (yy < 0 || yy > 191) continue;
#pragma unroll
        for (int dx = -1; dx <= 1; ++dx) {
            const int xx = x + dx;
            if (xx < 0 || xx > 191) continue;
            acc += img[yy*WW + xx] * wc[(dy+1)*3 + (dx+1)];
        }
    }
    g[bc*NPIX + y*WW + x] = gelu_f(acc);
}

// ---------------------------------------------------------------------------
// Per-batch Gram G1 = X1 * X1^T: partial per 256-pixel chunk.
// ---------------------------------------------------------------------------
__global__ __launch_bounds__(256) void k_gram_part(
    const float* __restrict__ x1p, float* __restrict__ part)
{
    extern __shared__ float lt[];     // [256][68]
    const int chunk = blockIdx.x, b = blockIdx.y, t = threadIdx.x;
    const int gbase = b * (C*NPIX) + chunk * 256;
    for (int idx = t; idx < C*256; idx += 256) {
        const int c = idx >> 8, n = idx & 255;
        lt[n*68 + c] = x1p[gbase + c*NPIX + n];
    }
    __syncthreads();
    const int ti = t & 15, tj = t >> 4;
    float acc[4][4];
#pragma unroll
    for (int r = 0; r < 4; ++r)
#pragma unroll
        for (int s = 0; s < 4; ++s) acc[r][s] = 0.f;
    for (int n = 0; n < 256; ++n) {
        const float4 av = *reinterpret_cast<const float4*>(&lt[n*68 + 4*ti]);
        const float4 bv = *reinterpret_cast<const float4*>(&lt[n*68 + 4*tj]);
        const float ar[4] = {av.x, av.y, av.z, av.w};
        const float br[4] = {bv.x, bv.y, bv.z, bv.w};
#pragma unroll
        for (int r = 0; r < 4; ++r)
#pragma unroll
            for (int s = 0; s < 4; ++s) acc[r][s] += ar[r] * br[s];
    }
    float* pb = part + (b*144 + chunk)*4096;
#pragma unroll
    for (int r = 0; r < 4; ++r)
#pragma unroll
        for (int s = 0; s < 4; ++s) pb[(4*ti+r)*64 + (4*tj+s)] = acc[r][s];
}

__global__ __launch_bounds__(256) void k_gram_reduce(
    const float* __restrict__ part, float* __restrict__ G1)
{
    const int flat = blockIdx.x*256 + threadIdx.x;   // < 16384
    const int b = flat >> 12, ij = flat & 4095;
    float s = 0.f;
    for (int ch = 0; ch < 144; ++ch) s += part[(b*144+ch)*4096 + ij];
    G1[flat] = s;
}

// ---------------------------------------------------------------------------
// Channel-attention collapse: per batch, M2 = Wp * blockdiag(attn) * Wv.
// ---------------------------------------------------------------------------
__global__ __launch_bounds__(256) void k_attn_small(
    const float* __restrict__ G1a, const float* __restrict__ Wq,
    const float* __restrict__ Wk, const float* __restrict__ Wv,
    const float* __restrict__ Wp, const float* __restrict__ temp,
    float* __restrict__ M2)
{
    extern __shared__ float sm[];
    float* g1 = sm;
    float* wa = sm + 4096;
    float* wb = sm + 8192;
    float* u  = sm + 12288;
    float* at = sm + 16384;
    float* nq = sm + 18432;
    float* nk = sm + 18496;
    const int b = blockIdx.x, t = threadIdx.x;
    const float* G = G1a + b*4096;
    for (int i = t; i < 4096; i += 256) { g1[i] = G[i]; wa[i] = Wq[i]; wb[i] = Wk[i]; }
    __syncthreads();
    {
        const int r = t >> 2, q4 = t & 3;
        for (int cc = q4*16; cc < q4*16 + 16; ++cc) {
            float s = 0.f;
            for (int k = 0; k < 64; ++k) s += wa[r*64+k] * g1[k*64+cc];
            u[r*64+cc] = s;
        }
    }
    __syncthreads();
    {
        const int d = t >> 2, kq = t & 3;
        float p = 0.f;
        for (int k = kq*16; k < kq*16 + 16; ++k) {
            float tk = 0.f;
            for (int c2 = 0; c2 < 64; ++c2) tk += g1[k*64+c2] * wb[d*64+c2];
            p += wb[d*64+k] * tk;
        }
        p += __shfl_xor(p, 1);
        p += __shfl_xor(p, 2);
        if (kq == 0) nk[d] = sqrtf(fmaxf(p, 0.f));
    }
    if (t < 64) {
        float s = 0.f;
        for (int c2 = 0; c2 < 64; ++c2) s += u[t*64+c2] * wa[t*64+c2];
        nq[t] = sqrtf(fmaxf(s, 0.f));
    }
    __syncthreads();
    if (t < 64) {
        const int gI = t >> 5;
        const float tg = temp[gI];
        const float dq = fmaxf(nq[t], 1e-12f);
        float row[32];
        float mx = -1e30f;
#pragma unroll
        for (int d2 = 0; d2 < 32; ++d2) {
            const int dd = gI*32 + d2;
            float s = 0.f;
            for (int c2 = 0; c2 < 64; ++c2) s += u[t*64+c2] * wb[dd*64+c2];
            s = s * tg / (dq * fmaxf(nk[dd], 1e-12f));
            row[d2] = s; mx = fmaxf(mx, s);
        }
        float se = 0.f;
#pragma unroll
        for (int d2 = 0; d2 < 32; ++d2) { row[d2] = __expf(row[d2]-mx); se += row[d2]; }
        const float inv = 1.f / se;
#pragma unroll
        for (int d2 = 0; d2 < 32; ++d2) at[t*32+d2] = row[d2]*inv;
    }
    __syncthreads();
    for (int i = t; i < 4096; i += 256) { wa[i] = Wv[i]; wb[i] = Wp[i]; }
    __syncthreads();
    {
        const int m = t >> 2, q4 = t & 3, gI = m >> 5;
        for (int e = q4*16; e < q4*16 + 16; ++e) {
            float s = 0.f;
#pragma unroll
            for (int d2 = 0; d2 < 32; ++d2) s += at[m*32+d2] * wa[(gI*32+d2)*64 + e];
            g1[m*64+e] = s;
        }
    }
    __syncthreads();
    {
        const int o = t >> 2, q4 = t & 3;
        for (int e = q4*16; e < q4*16 + 16; ++e) {
            float s = 0.f;
            for (int m = 0; m < 64; ++m) s += wb[o*64+m] * g1[m*64+e];
            M2[b*4096 + o*64+e] = s;
        }
    }
}

// ---------------------------------------------------------------------------
// Small weight-folding products:
//  0: Wtr = rq^T rk   1: Wtc = cq^T ck
//  2: Wf2p = gr * Wf[:,64:128] @ rv   3: Wf3p = gc * Wf[:,128:192] @ cv
//  4: Wfx  = Wf[:,64:128] + Wf[:,128:192]
// ---------------------------------------------------------------------------
__global__ __launch_bounds__(256) void k_small_mats(
    const float* __restrict__ rq, const float* __restrict__ rk,
    const float* __restrict__ cq, const float* __restrict__ ck,
    const float* __restrict__ fw, const float* __restrict__ rv,
    const float* __restrict__ cv, const float* __restrict__ rg,
    const float* __restrict__ cg,
    float* __restrict__ Wtr, float* __restrict__ Wtc,
    float* __restrict__ Wf2p, float* __restrict__ Wf3p,
    float* __restrict__ Wfx)
{
    const int which = blockIdx.x, t = threadIdx.x;
    const int a = t >> 2, b0 = (t & 3) * 16;
    if (which <= 1) {
        const float* Q = which ? cq : rq;
        const float* Kw = which ? ck : rk;
        float* O = which ? Wtc : Wtr;
        for (int b = b0; b < b0 + 16; ++b) {
            float s = 0.f;
            for (int co = 0; co < 64; ++co) s += Q[co*64 + a] * Kw[co*64 + b];
            O[a*64 + b] = s;
        }
    } else if (which <= 3) {
        const float* Vw = (which == 2) ? rv : cv;
        const float g = (which == 2) ? rg[0] : cg[0];
        const int off = (which == 2) ? 64 : 128;
        float* O = (which == 2) ? Wf2p : Wf3p;
        for (int b = b0; b < b0 + 16; ++b) {
            float s = 0.f;
            for (int m = 0; m < 64; ++m) s += fw[a*192 + off + m] * Vw[m*64 + b];
            O[a*64 + b] = g * s;
        }
    } else {
        for (int b = b0; b < b0 + 16; ++b)
            Wfx[a*64 + b] = fw[a*192 + 64 + b] + fw[a*192 + 128 + b];
    }
}

// ---------------------------------------------------------------------------
// FUSED per-line attention: Y = Wt@X (LDS), S = X^T Y, P = softmax_rows(S)
// kept entirely in LDS, Z[c][i] = sum_j U[c][j] * P[i][j] -> global.
// grid (192, B), block = 256.
// LDS (floats): phase A: Xl[64][196]@0, Yl[64][196]@12544, Wl[64][68]@25088
//               phase B: Pl[192][196]@0 (overlay only; NO U staging)
// dyn LDS = 37632*4 = 150528 B -> 1 block/CU.
// Phase-5 redesign (R4 post-mortem: the per-CU LDS issue pipe is the cap --
// 16 b128 reads vs 192 VALU-cy per jq = the measured 50% VALUBusy ceiling):
//   U is read DIRECTLY from global (L2-hot, 16-lane-broadcast coalesced);
//   Ul staging + all 12 in-loop barriers removed. LDS pipe load per jq drops
//   16->12 b128 reads; the 48-iteration loop is barrier-free so the compiler
//   software-pipelines loads across iterations and waves drift freely.
// Z store pattern kept bit-identical to R3 (WRITE_SIZE clean there).
// ---------------------------------------------------------------------------
#define SP 196
__global__ __launch_bounds__(256, 1) void k_attn_fused(
    const float* __restrict__ X, const float* __restrict__ Wt,
    const float* __restrict__ U, float* __restrict__ Z)
{
    extern __shared__ float sm[];
    float* Xl = sm;                    // [64][196]
    float* Yl = sm + 12544;            // [64][196]
    float* Wl = sm + 25088;            // [64][68]  Wl[c2][c] = Wt[c][c2]
    float* Pl = sm;                    // [192][196] overlay (phase B)
    float* red  = sm;                  // [192][17] overlay on Xl (softmax)
    float* mrow = sm + 192*17;         // 192
    float* lrow = sm + 192*17 + 192;   // 192
    const int t = threadIdx.x;
    const int h = blockIdx.x, b = blockIdx.y;
    const size_t gbase = (size_t)b*(C*NPIX) + (size_t)h*WW;

    // --- phase 0: load X line + W~ ---
#pragma unroll 4
    for (int k = 0; k < 48; ++k) {
        const int idx = k*256 + t;
        const int c = idx / 192, j = idx - c*192;
        Xl[c*SP + j] = X[gbase + (size_t)c*NPIX + j];
    }
#pragma unroll
    for (int k = 0; k < 16; ++k) {
        const int idx = k*256 + t;                 // idx = a*64 + c2
        Wl[(idx & 63)*68 + (idx >> 6)] = Wt[idx];
    }
    __syncthreads();

    // --- phase 1: Y = Wt @ X, 16x16 thread grid, 4x12 register tiles ---
    {
        const int tc = t & 15, tjy = t >> 4;
        const int c0 = 4*tc, j0y = 12*tjy;
        float accy[4][12];
#pragma unroll
        for (int k = 0; k < 4; ++k)
#pragma unroll
            for (int m = 0; m < 12; ++m) accy[k][m] = 0.f;
        for (int c2 = 0; c2 < 64; ++c2) {
            const float4 w4 = *reinterpret_cast<const float4*>(&Wl[c2*68 + c0]);
            const float4 xa = *reinterpret_cast<const float4*>(&Xl[c2*SP + j0y]);
            const float4 xb = *reinterpret_cast<const float4*>(&Xl[c2*SP + j0y + 4]);
            const float4 xc = *reinterpret_cast<const float4*>(&Xl[c2*SP + j0y + 8]);
            const float wr[4]  = {w4.x, w4.y, w4.z, w4.w};
            const float xr[12] = {xa.x,xa.y,xa.z,xa.w, xb.x,xb.y,xb.z,xb.w,
                                  xc.x,xc.y,xc.z,xc.w};
#pragma unroll
            for (int k = 0; k < 4; ++k)
#pragma unroll
                for (int m = 0; m < 12; ++m) accy[k][m] += wr[k] * xr[m];
        }
#pragma unroll
        for (int k = 0; k < 4; ++k) {
            float4 o0, o1, o2;
            o0.x = accy[k][0]; o0.y = accy[k][1]; o0.z = accy[k][2];  o0.w = accy[k][3];
            o1.x = accy[k][4]; o1.y = accy[k][5]; o1.z = accy[k][6];  o1.w = accy[k][7];
            o2.x = accy[k][8]; o2.y = accy[k][9]; o2.z = accy[k][10]; o2.w = accy[k][11];
            float* yr = &Yl[(c0+k)*SP + j0y];
            *reinterpret_cast<float4*>(yr)     = o0;
            *reinterpret_cast<float4*>(yr + 4) = o1;
            *reinterpret_cast<float4*>(yr + 8) = o2;
        }
    }
    __syncthreads();

    // --- phase 2: S = X^T Y, 12x12 per thread ---
    const int ti = t & 15, tj = t >> 4;
    const int i0 = ti*12, j0 = tj*12;
    float acc[12][12];
#pragma unroll
    for (int r = 0; r < 12; ++r)
#pragma unroll
        for (int s = 0; s < 12; ++s) acc[r][s] = 0.f;
#pragma unroll 2
    for (int c = 0; c < 64; ++c) {
        const float4 xa = *reinterpret_cast<const float4*>(&Xl[c*SP + i0]);
        const float4 xb = *reinterpret_cast<const float4*>(&Xl[c*SP + i0 + 4]);
        const float4 xc = *reinterpret_cast<const float4*>(&Xl[c*SP + i0 + 8]);
        const float4 ya = *reinterpret_cast<const float4*>(&Yl[c*SP + j0]);
        const float4 yb = *reinterpret_cast<const float4*>(&Yl[c*SP + j0 + 4]);
        const float4 yc = *reinterpret_cast<const float4*>(&Yl[c*SP + j0 + 8]);
        const float xr[12] = {xa.x,xa.y,xa.z,xa.w, xb.x,xb.y,xb.z,xb.w, xc.x,xc.y,xc.z,xc.w};
        const float yr[12] = {ya.x,ya.y,ya.z,ya.w, yb.x,yb.y,yb.z,yb.w, yc.x,yc.y,yc.z,yc.w};
#pragma unroll
        for (int r = 0; r < 12; ++r)
#pragma unroll
            for (int s = 0; s < 12; ++s) acc[r][s] += xr[r] * yr[s];
    }
    __syncthreads();   // Xl/Yl dead; red overlays Xl

    // --- phase 3: softmax over rows ---
#pragma unroll
    for (int r = 0; r < 12; ++r) {
        float pm = acc[r][0];
#pragma unroll
        for (int s = 1; s < 12; ++s) pm = fmaxf(pm, acc[r][s]);
        red[(i0 + r)*17 + tj] = pm;
    }
    __syncthreads();
    if (t < 192) {
        float m = red[t*17];
#pragma unroll
        for (int k = 1; k < 16; ++k) m = fmaxf(m, red[t*17 + k]);
        mrow[t] = m;
    }
    __syncthreads();
#pragma unroll
    for (int r = 0; r < 12; ++r) {
        const float mi = mrow[i0 + r];
        float ps = 0.f;
#pragma unroll
        for (int s = 0; s < 12; ++s) {
            acc[r][s] = __expf(acc[r][s] - mi);
            ps += acc[r][s];
        }
        red[(i0 + r)*17 + tj] = ps;
    }
    __syncthreads();
    if (t < 192) {
        float l = 0.f;
#pragma unroll
        for (int k = 0; k < 16; ++k) l += red[t*17 + k];
        lrow[t] = 1.f / l;
    }
    __syncthreads();
    float invl[12];
#pragma unroll
    for (int r = 0; r < 12; ++r) invl[r] = lrow[i0 + r];
    __syncthreads();   // lrow/red read complete; Pl may now overwrite

    // --- phase 4: store normalized P into LDS ---
#pragma unroll
    for (int r = 0; r < 12; ++r) {
        const float inv = invl[r];
        float4 o0, o1, o2;
        o0.x = acc[r][0]*inv;  o0.y = acc[r][1]*inv;  o0.z = acc[r][2]*inv;  o0.w = acc[r][3]*inv;
        o1.x = acc[r][4]*inv;  o1.y = acc[r][5]*inv;  o1.z = acc[r][6]*inv;  o1.w = acc[r][7]*inv;
        o2.x = acc[r][8]*inv;  o2.y = acc[r][9]*inv;  o2.z = acc[r][10]*inv; o2.w = acc[r][11]*inv;
        float* pr = &Pl[(i0 + r)*SP + j0];
        *reinterpret_cast<float4*>(pr)     = o0;
        *reinterpret_cast<float4*>(pr + 4) = o1;
        *reinterpret_cast<float4*>(pr + 8) = o2;
    }
    __syncthreads();

    // --- phase 5: Z[c][i] = sum_j U[c][j] * P[i][j]; U streamed straight
    //     from global (L2-hot, 16-lane broadcast per load), P from LDS.
    //     Barrier-free: compiler software-pipelines across the 48 iters. ---
    const int ci = t & 15, ii = t >> 4;
    const int c0z = 4*ci, i0z = 12*ii;
    const float* Ub = U + gbase;
    float accz[4][12];
#pragma unroll
    for (int k = 0; k < 4; ++k)
#pragma unroll
        for (int m = 0; m < 12; ++m) accz[k][m] = 0.f;
#pragma unroll 2
    for (int jq = 0; jq < 48; ++jq) {
        const int j4 = 4*jq;
        float4 u4[4], p4[12];
#pragma unroll
        for (int k = 0; k < 4; ++k)
            u4[k] = *reinterpret_cast<const float4*>(&Ub[(size_t)(c0z+k)*NPIX + j4]);
#pragma unroll
        for (int m = 0; m < 12; ++m)
            p4[m] = *reinterpret_cast<const float4*>(&Pl[(i0z+m)*SP + j4]);
#pragma unroll
        for (int k = 0; k < 4; ++k)
#pragma unroll
            for (int m = 0; m < 12; ++m) {
                accz[k][m] += u4[k].x * p4[m].x + u4[k].y * p4[m].y
                            + u4[k].z * p4[m].z + u4[k].w * p4[m].w;
            }
    }
#pragma unroll
    for (int k = 0; k < 4; ++k) {
        float* zr = Z + gbase + (size_t)(c0z + k)*NPIX + i0z;
        float4 o0, o1, o2;
        o0.x = accz[k][0]; o0.y = accz[k][1]; o0.z = accz[k][2];  o0.w = accz[k][3];
        o1.x = accz[k][4]; o1.y = accz[k][5]; o1.z = accz[k][6];  o1.w = accz[k][7];
        o2.x = accz[k][8]; o2.y = accz[k][9]; o2.z = accz[k][10]; o2.w = accz[k][11];
        *reinterpret_cast<float4*>(zr)     = o0;
        *reinterpret_cast<float4*>(zr + 4) = o1;
        *reinterpret_cast<float4*>(zr + 8) = o2;
    }
}

// ---------------------------------------------------------------------------
// HW transpose per image: out[img][x][y] = in[img][y][x]. grid (6,6,B*C).
// ---------------------------------------------------------------------------
__global__ __launch_bounds__(256) void k_transpose(
    const float* __restrict__ in, float* __restrict__ out)
{
    __shared__ float tile[32][33];
    const int tx = threadIdx.x & 31, ty = threadIdx.x >> 5;
    const int x0 = blockIdx.x*32, y0 = blockIdx.y*32;
    const float* img = in + blockIdx.z * NPIX;
    float* og = out + blockIdx.z * NPIX;
#pragma unroll
    for (int r = ty; r < 32; r += 8) tile[r][tx] = img[(y0+r)*WW + x0+tx];
    __syncthreads();
#pragma unroll
    for (int r = ty; r < 32; r += 8) og[(x0+r)*WW + (y0+tx)] = tile[tx][r];
}

// ---------------------------------------------------------------------------
extern "C" void kernel_launch(void* const* d_in, const int* in_sizes, int n_in,
                              void* d_out, int out_size, void* d_ws, size_t ws_size,
                              hipStream_t stream) {
    const float* x       = (const float*)d_in[0];
    const float* pw_w    = (const float*)d_in[1];
    const float* dw_w    = (const float*)d_in[2];
    const float* dw_b    = (const float*)d_in[3];
    const float* conv2_w = (const float*)d_in[4];
    const float* conv2_b = (const float*)d_in[5];
    const float* conv0_w = (const float*)d_in[6];
    const float* conv0_b = (const float*)d_in[7];
    const float* attq    = (const float*)d_in[8];
    const float* attk    = (const float*)d_in[9];
    const float* attv    = (const float*)d_in[10];
    const float* attp    = (const float*)d_in[11];
    const float* temp    = (const float*)d_in[12];
    const float* rq      = (const float*)d_in[13];
    const float* rk      = (const float*)d_in[14];
    const float* rv      = (const float*)d_in[15];
    const float* rg      = (const float*)d_in[16];
    const float* cq      = (const float*)d_in[17];
    const float* ck      = (const float*)d_in[18];
    const float* cv      = (const float*)d_in[19];
    const float* cg      = (const float*)d_in[20];
    const float* fw      = (const float*)d_in[21];
    const float* fb      = (const float*)d_in[22];

    float* ws = (float*)d_ws;
    float* A  = ws;                 // t0 -> x1 (lives to end)
    float* Bf = ws + (size_t)ST;    // g -> out1
    float* Cf = ws + 2*(size_t)ST;  // x1t -> Z2
    float* Df = ws + 3*(size_t)ST;  // out1t -> Z3
    float* Ef = ws + 4*(size_t)ST;  // Z3t -> final pass-1 tmp
    float* partials = ws + 5*(size_t)ST;   // 576*4096 = 2359296 floats
    float* G1 = partials + 576*4096;       // 16384
    float* M2 = G1 + 16384;                // 16384
    float* Wtr  = M2 + 16384;              // 5 x 4096
    float* Wtc  = Wtr + 4096;
    float* Wf2p = Wtc + 4096;
    float* Wf3p = Wf2p + 4096;
    float* Wfx  = Wf3p + 4096;

    const size_t need = ((size_t)5*ST + 576*4096 + 16384 + 16384 + 5*4096)
                        * sizeof(float);
    if (ws_size < need) {
        fprintf(stderr, "kernel_launch: ws_size %zu < needed %zu\n", ws_size, need);
        return;
    }

    (void)hipFuncSetAttribute((const void*)k_gram_part,
        hipFuncAttributeMaxDynamicSharedMemorySize, 69632);
    (void)hipFuncSetAttribute((const void*)k_attn_small,
        hipFuncAttributeMaxDynamicSharedMemorySize, 74240);
    (void)hipFuncSetAttribute((const void*)k_attn_fused,
        hipFuncAttributeMaxDynamicSharedMemorySize, 150528);

    const dim3 blk256(256), blk192(192);
    const dim3 gconv(NPIX/256, BB);      // (144, 4)
    const dim3 gline(HH, BB);            // (192, 4)
    const dim3 gtr(6, 6, BB*C);

    // 0) fold weights
    k_small_mats<<<dim3(5), blk256, 0, stream>>>(rq, rk, cq, ck, fw, rv, cv,
                                                 rg, cg, Wtr, Wtc, Wf2p, Wf3p, Wfx);
    // 1) A = pw_w @ x
    k_conv<false,false,false><<<gconv, blk256, 0, stream>>>(
        x, nullptr, pw_w, nullptr, nullptr, nullptr, nullptr, A, 64, 64);
    // 2) B = gelu(dw3x3(A) + dw_b)
    k_dw<<<dim3(HH, BB*C), blk192, 0, stream>>>(A, dw_w, dw_b, Bf);
    // 3) A = x1 = conv2@B + conv0@x + conv2_b + conv0_b
    k_conv<true,false,false><<<gconv, blk256, 0, stream>>>(
        Bf, x, conv2_w, conv0_w, conv2_b, conv0_b, nullptr, A, 64, 64);
    // 4) channel attention collapse -> M2
    k_gram_part<<<gconv, blk256, 69632, stream>>>(A, partials);
    k_gram_reduce<<<dim3(64), blk256, 0, stream>>>(partials, G1);
    k_attn_small<<<dim3(BB), blk256, 74240, stream>>>(G1, attq, attk, attv, attp, temp, M2);
    // 5) B = out1 = M2[b] @ x1
    k_conv<false,true,false><<<gconv, blk256, 0, stream>>>(
        A, nullptr, M2, nullptr, nullptr, nullptr, nullptr, Bf, 64, 64);
    // 6) C = x1t, D = out1t
    k_transpose<<<gtr, blk256, 0, stream>>>(A, Cf);
    k_transpose<<<gtr, blk256, 0, stream>>>(Bf, Df);
    // 7) col attention fused: E = Z3t
    k_attn_fused<<<gline, blk256, 150528, stream>>>(Cf, Wtc, Df, Ef);
    // 8) D = Z3 = transpose(Z3t)
    k_transpose<<<gtr, blk256, 0, stream>>>(Ef, Df);
    // 9) row attention fused: C = Z2
    k_attn_fused<<<gline, blk256, 150528, stream>>>(A, Wtr, Bf, Cf);
    // 10) final fuse (folded): out = gelu(Wf1@out1 + Wf2p@Z2 + Wf3p@Z3
    //                                      + Wfx@x1 + fb)
    k_conv<true,false,false><<<gconv, blk256, 0, stream>>>(
        Bf, Cf, fw, Wf2p, fb, nullptr, nullptr, Ef, 192, 64);
    k_conv<true,false,true><<<gconv, blk256, 0, stream>>>(
        Df, A, Wf3p, Wfx, nullptr, nullptr, Ef, (float*)d_out, 64, 64);
}

// Round 6
// 1105.025 us; speedup vs baseline: 1.1257x; 1.0451x over previous
//
#include <hip/hip_runtime.h>
#include <hip/hip_fp16.h>
#include <cstdio>

#define BB 4
#define C 64
#define HH 192
#define WW 192
#define NPIX (HH*WW)            /* 36864 */
#define ST (BB*C*NPIX)          /* 9437184 floats per tensor */

__device__ __forceinline__ float gelu_f(float v) {
    return 0.5f * v * (1.0f + erff(v * 0.70710678118654752440f));
}

// ---------------------------------------------------------------------------
// Generic 1x1 conv over NCHW: out[b,o,n] = W1@in1 (+ W2@in2) (+bias1)(+bias2)
// (+res)(gelu). grid = (NPIX/256, B), block = 256. out1 never aliases inputs.
// ---------------------------------------------------------------------------
template<bool TWO_IN, bool PERB, bool DO_GELU>
__global__ __launch_bounds__(256) void k_conv(
    const float* __restrict__ in1, const float* __restrict__ in2,
    const float* __restrict__ W1, const float* __restrict__ W2,
    const float* __restrict__ bias1, const float* __restrict__ bias2,
    const float* __restrict__ res, float* __restrict__ out1,
    int ldw1, int ldw2)
{
    const int n = blockIdx.x * 256 + threadIdx.x;
    const int b = blockIdx.y;
    const int base = b * (C * NPIX) + n;
    float xv[C];
#pragma unroll
    for (int c = 0; c < C; ++c) xv[c] = in1[base + c * NPIX];
    float yv[TWO_IN ? C : 1];
    if (TWO_IN) {
#pragma unroll
        for (int c = 0; c < C; ++c) yv[c] = in2[base + c * NPIX];
    }
    const float* w1 = W1 + (PERB ? b * C * C : 0);
    for (int o = 0; o < C; ++o) {
        const float* wr = w1 + o * ldw1;
        float a0 = 0.f, a1 = 0.f, a2 = 0.f, a3 = 0.f;
#pragma unroll
        for (int c = 0; c < C; c += 4) {
            a0 += wr[c+0] * xv[c+0];
            a1 += wr[c+1] * xv[c+1];
            a2 += wr[c+2] * xv[c+2];
            a3 += wr[c+3] * xv[c+3];
        }
        if (TWO_IN) {
            const float* wr2 = W2 + o * ldw2;
#pragma unroll
            for (int c = 0; c < C; c += 4) {
                a0 += wr2[c+0] * yv[c+0];
                a1 += wr2[c+1] * yv[c+1];
                a2 += wr2[c+2] * yv[c+2];
                a3 += wr2[c+3] * yv[c+3];
            }
        }
        float acc = (a0 + a1) + (a2 + a3);
        if (bias1) acc += bias1[o];
        if (bias2) acc += bias2[o];
        const int ob = base + o * NPIX;
        if (res) acc += res[ob];
        if (DO_GELU) acc = gelu_f(acc);
        out1[ob] = acc;
    }
}

// ---------------------------------------------------------------------------
// Depthwise 3x3 (pad 1) + bias + GELU.  grid = (H, B*C), block = 192 (=W).
// ---------------------------------------------------------------------------
__global__ __launch_bounds__(192) void k_dw(
    const float* __restrict__ t0, const float* __restrict__ w,
    const float* __restrict__ bias, float* __restrict__ g)
{
    const int x = threadIdx.x;
    const int y = blockIdx.x;
    const int bc = blockIdx.y;
    const int c = bc & 63;
    const float* img = t0 + bc * NPIX;
    const float* wc = w + c * 9;
    float acc = bias[c];
#pragma unroll
    for (int dy = -1; dy <= 1; ++dy) {
        const int yy = y + dy;
        if (yy < 0 || yy > 191) continue;
#pragma unroll
        for (int dx = -1; dx <= 1; ++dx) {
            const int xx = x + dx;
            if (xx < 0 || xx > 191) continue;
            acc += img[yy*WW + xx] * wc[(dy+1)*3 + (dx+1)];
        }
    }
    g[bc*NPIX + y*WW + x] = gelu_f(acc);
}

// ---------------------------------------------------------------------------
// Per-batch Gram G1 = X1 * X1^T: partial per 256-pixel chunk.
// ---------------------------------------------------------------------------
__global__ __launch_bounds__(256) void k_gram_part(
    const float* __restrict__ x1p, float* __restrict__ part)
{
    extern __shared__ float lt[];     // [256][68]
    const int chunk = blockIdx.x, b = blockIdx.y, t = threadIdx.x;
    const int gbase = b * (C*NPIX) + chunk * 256;
    for (int idx = t; idx < C*256; idx += 256) {
        const int c = idx >> 8, n = idx & 255;
        lt[n*68 + c] = x1p[gbase + c*NPIX + n];
    }
    __syncthreads();
    const int ti = t & 15, tj = t >> 4;
    float acc[4][4];
#pragma unroll
    for (int r = 0; r < 4; ++r)
#pragma unroll
        for (int s = 0; s < 4; ++s) acc[r][s] = 0.f;
    for (int n = 0; n < 256; ++n) {
        const float4 av = *reinterpret_cast<const float4*>(&lt[n*68 + 4*ti]);
        const float4 bv = *reinterpret_cast<const float4*>(&lt[n*68 + 4*tj]);
        const float ar[4] = {av.x, av.y, av.z, av.w};
        const float br[4] = {bv.x, bv.y, bv.z, bv.w};
#pragma unroll
        for (int r = 0; r < 4; ++r)
#pragma unroll
            for (int s = 0; s < 4; ++s) acc[r][s] += ar[r] * br[s];
    }
    float* pb = part + (b*144 + chunk)*4096;
#pragma unroll
    for (int r = 0; r < 4; ++r)
#pragma unroll
        for (int s = 0; s < 4; ++s) pb[(4*ti+r)*64 + (4*tj+s)] = acc[r][s];
}

__global__ __launch_bounds__(256) void k_gram_reduce(
    const float* __restrict__ part, float* __restrict__ G1)
{
    const int flat = blockIdx.x*256 + threadIdx.x;   // < 16384
    const int b = flat >> 12, ij = flat & 4095;
    float s = 0.f;
    for (int ch = 0; ch < 144; ++ch) s += part[(b*144+ch)*4096 + ij];
    G1[flat] = s;
}

// ---------------------------------------------------------------------------
// Channel-attention collapse: per batch, M2 = Wp * blockdiag(attn) * Wv.
// ---------------------------------------------------------------------------
__global__ __launch_bounds__(256) void k_attn_small(
    const float* __restrict__ G1a, const float* __restrict__ Wq,
    const float* __restrict__ Wk, const float* __restrict__ Wv,
    const float* __restrict__ Wp, const float* __restrict__ temp,
    float* __restrict__ M2)
{
    extern __shared__ float sm[];
    float* g1 = sm;
    float* wa = sm + 4096;
    float* wb = sm + 8192;
    float* u  = sm + 12288;
    float* at = sm + 16384;
    float* nq = sm + 18432;
    float* nk = sm + 18496;
    const int b = blockIdx.x, t = threadIdx.x;
    const float* G = G1a + b*4096;
    for (int i = t; i < 4096; i += 256) { g1[i] = G[i]; wa[i] = Wq[i]; wb[i] = Wk[i]; }
    __syncthreads();
    {
        const int r = t >> 2, q4 = t & 3;
        for (int cc = q4*16; cc < q4*16 + 16; ++cc) {
            float s = 0.f;
            for (int k = 0; k < 64; ++k) s += wa[r*64+k] * g1[k*64+cc];
            u[r*64+cc] = s;
        }
    }
    __syncthreads();
    {
        const int d = t >> 2, kq = t & 3;
        float p = 0.f;
        for (int k = kq*16; k < kq*16 + 16; ++k) {
            float tk = 0.f;
            for (int c2 = 0; c2 < 64; ++c2) tk += g1[k*64+c2] * wb[d*64+c2];
            p += wb[d*64+k] * tk;
        }
        p += __shfl_xor(p, 1);
        p += __shfl_xor(p, 2);
        if (kq == 0) nk[d] = sqrtf(fmaxf(p, 0.f));
    }
    if (t < 64) {
        float s = 0.f;
        for (int c2 = 0; c2 < 64; ++c2) s += u[t*64+c2] * wa[t*64+c2];
        nq[t] = sqrtf(fmaxf(s, 0.f));
    }
    __syncthreads();
    if (t < 64) {
        const int gI = t >> 5;
        const float tg = temp[gI];
        const float dq = fmaxf(nq[t], 1e-12f);
        float row[32];
        float mx = -1e30f;
#pragma unroll
        for (int d2 = 0; d2 < 32; ++d2) {
            const int dd = gI*32 + d2;
            float s = 0.f;
            for (int c2 = 0; c2 < 64; ++c2) s += u[t*64+c2] * wb[dd*64+c2];
            s = s * tg / (dq * fmaxf(nk[dd], 1e-12f));
            row[d2] = s; mx = fmaxf(mx, s);
        }
        float se = 0.f;
#pragma unroll
        for (int d2 = 0; d2 < 32; ++d2) { row[d2] = __expf(row[d2]-mx); se += row[d2]; }
        const float inv = 1.f / se;
#pragma unroll
        for (int d2 = 0; d2 < 32; ++d2) at[t*32+d2] = row[d2]*inv;
    }
    __syncthreads();
    for (int i = t; i < 4096; i += 256) { wa[i] = Wv[i]; wb[i] = Wp[i]; }
    __syncthreads();
    {
        const int m = t >> 2, q4 = t & 3, gI = m >> 5;
        for (int e = q4*16; e < q4*16 + 16; ++e) {
            float s = 0.f;
#pragma unroll
            for (int d2 = 0; d2 < 32; ++d2) s += at[m*32+d2] * wa[(gI*32+d2)*64 + e];
            g1[m*64+e] = s;
        }
    }
    __syncthreads();
    {
        const int o = t >> 2, q4 = t & 3;
        for (int e = q4*16; e < q4*16 + 16; ++e) {
            float s = 0.f;
            for (int m = 0; m < 64; ++m) s += wb[o*64+m] * g1[m*64+e];
            M2[b*4096 + o*64+e] = s;
        }
    }
}

// ---------------------------------------------------------------------------
// Small weight-folding products:
//  0: Wtr = rq^T rk   1: Wtc = cq^T ck
//  2: Wf2p = gr * Wf[:,64:128] @ rv   3: Wf3p = gc * Wf[:,128:192] @ cv
//  4: Wfx  = Wf[:,64:128] + Wf[:,128:192]
// ---------------------------------------------------------------------------
__global__ __launch_bounds__(256) void k_small_mats(
    const float* __restrict__ rq, const float* __restrict__ rk,
    const float* __restrict__ cq, const float* __restrict__ ck,
    const float* __restrict__ fw, const float* __restrict__ rv,
    const float* __restrict__ cv, const float* __restrict__ rg,
    const float* __restrict__ cg,
    float* __restrict__ Wtr, float* __restrict__ Wtc,
    float* __restrict__ Wf2p, float* __restrict__ Wf3p,
    float* __restrict__ Wfx)
{
    const int which = blockIdx.x, t = threadIdx.x;
    const int a = t >> 2, b0 = (t & 3) * 16;
    if (which <= 1) {
        const float* Q = which ? cq : rq;
        const float* Kw = which ? ck : rk;
        float* O = which ? Wtc : Wtr;
        for (int b = b0; b < b0 + 16; ++b) {
            float s = 0.f;
            for (int co = 0; co < 64; ++co) s += Q[co*64 + a] * Kw[co*64 + b];
            O[a*64 + b] = s;
        }
    } else if (which <= 3) {
        const float* Vw = (which == 2) ? rv : cv;
        const float g = (which == 2) ? rg[0] : cg[0];
        const int off = (which == 2) ? 64 : 128;
        float* O = (which == 2) ? Wf2p : Wf3p;
        for (int b = b0; b < b0 + 16; ++b) {
            float s = 0.f;
            for (int m = 0; m < 64; ++m) s += fw[a*192 + off + m] * Vw[m*64 + b];
            O[a*64 + b] = g * s;
        }
    } else {
        for (int b = b0; b < b0 + 16; ++b)
            Wfx[a*64 + b] = fw[a*192 + 64 + b] + fw[a*192 + 128 + b];
    }
}

// ---------------------------------------------------------------------------
// FUSED per-line attention, 2 blocks/CU via fp16 LDS intermediates.
//   Y = Wt @ X   (fp32 math, stored fp16 in LDS; Wt read from global/L2)
//   S = X^T Y    (fp32 12x12 register tiles)
//   P~ = exp(S - rowmax) stored fp16 (unnormalized); 1/l kept in lrow (fp32)
//   Z[c][i] = (1/l_i) * sum_j U[c][j] P~[i][j]  (U streamed from global/L2)
// grid (192, B), block = 256.
// LDS layout (bytes):
//   phase A: Xl fp32 [64][196] @0 (50176) + Ylh fp16 [64][196] @50176 (25088)
//   phase B: Plh fp16 [192][196] @0 (75264) exact overlay of Xl+Ylh
//   softmax scratch red[192][17]+mrow overlay dead Xl; lrow @75264 (768)
// dyn LDS = 76032 B -> 2 blocks/CU -> 2 waves/SIMD (vs 1 before): block k+1's
// phase-0 HBM drain and barrier stalls overlap block k's compute, with the
// proven 12x12 fp32 tile structure intact (R1/R4 failures kept occupancy but
// degraded intensity; this keeps both).
// Precision: scales are tiny (S ~ +-0.5); fp16 storage of Y adds ~1e-4 rel to
// P, fp16 P~ adds <= max|U|*2^-11 to Z. All accumulation fp32.
// ---------------------------------------------------------------------------
#define SP 196
__global__ __launch_bounds__(256, 2) void k_attn_fused(
    const float* __restrict__ X, const float* __restrict__ Wt,
    const float* __restrict__ U, float* __restrict__ Z)
{
    extern __shared__ float sm[];
    float* Xl = sm;                                   // [64][196] fp32
    __half* Ylh = reinterpret_cast<__half*>(sm + 12544);  // [64][196] fp16
    __half* Plh = reinterpret_cast<__half*>(sm);      // [192][196] fp16 overlay
    float* red  = sm;                                 // [192][17] overlay (ph3)
    float* mrow = sm + 3264;                          // 192 (in dead Xl)
    float* lrow = sm + 18816;                         // 192, persistent @75264B
    const int t = threadIdx.x;
    const int h = blockIdx.x, b = blockIdx.y;
    const size_t gbase = (size_t)b*(C*NPIX) + (size_t)h*WW;

    // --- phase 0: load X line ---
#pragma unroll 4
    for (int k = 0; k < 48; ++k) {
        const int idx = k*256 + t;
        const int c = idx / 192, j = idx - c*192;
        Xl[c*SP + j] = X[gbase + (size_t)c*NPIX + j];
    }
    __syncthreads();

    // --- phase 1: Y = Wt @ X (fp32 math), store fp16. Wt from global. ---
    {
        const int tc = t & 15, tjy = t >> 4;
        const int c0 = 4*tc, j0y = 12*tjy;
        float accy[4][12];
#pragma unroll
        for (int k = 0; k < 4; ++k)
#pragma unroll
            for (int m = 0; m < 12; ++m) accy[k][m] = 0.f;
        for (int a = 0; a < 64; ++a) {
            const float4 w4 = *reinterpret_cast<const float4*>(&Wt[a*64 + c0]);
            const float4 xa = *reinterpret_cast<const float4*>(&Xl[a*SP + j0y]);
            const float4 xb = *reinterpret_cast<const float4*>(&Xl[a*SP + j0y + 4]);
            const float4 xc = *reinterpret_cast<const float4*>(&Xl[a*SP + j0y + 8]);
            const float wr[4]  = {w4.x, w4.y, w4.z, w4.w};
            const float xr[12] = {xa.x,xa.y,xa.z,xa.w, xb.x,xb.y,xb.z,xb.w,
                                  xc.x,xc.y,xc.z,xc.w};
#pragma unroll
            for (int k = 0; k < 4; ++k)
#pragma unroll
                for (int m = 0; m < 12; ++m) accy[k][m] += wr[k] * xr[m];
        }
#pragma unroll
        for (int k = 0; k < 4; ++k) {
            __half2* yr = reinterpret_cast<__half2*>(&Ylh[(c0+k)*SP + j0y]);
#pragma unroll
            for (int q = 0; q < 6; ++q)
                yr[q] = __floats2half2_rn(accy[k][2*q], accy[k][2*q+1]);
        }
    }
    __syncthreads();

    // --- phase 2: S = X^T Y, fp32 12x12 per thread (Y converted on read) ---
    const int ti = t & 15, tj = t >> 4;
    const int i0 = ti*12, j0 = tj*12;
    float acc[12][12];
#pragma unroll
    for (int r = 0; r < 12; ++r)
#pragma unroll
        for (int s = 0; s < 12; ++s) acc[r][s] = 0.f;
#pragma unroll 2
    for (int c = 0; c < 64; ++c) {
        const float4 xa = *reinterpret_cast<const float4*>(&Xl[c*SP + i0]);
        const float4 xb = *reinterpret_cast<const float4*>(&Xl[c*SP + i0 + 4]);
        const float4 xc = *reinterpret_cast<const float4*>(&Xl[c*SP + i0 + 8]);
        const __half2* yp = reinterpret_cast<const __half2*>(&Ylh[c*SP + j0]);
        const float2 y0 = __half22float2(yp[0]);
        const float2 y1 = __half22float2(yp[1]);
        const float2 y2 = __half22float2(yp[2]);
        const float2 y3 = __half22float2(yp[3]);
        const float2 y4 = __half22float2(yp[4]);
        const float2 y5 = __half22float2(yp[5]);
        const float xr[12] = {xa.x,xa.y,xa.z,xa.w, xb.x,xb.y,xb.z,xb.w, xc.x,xc.y,xc.z,xc.w};
        const float yr[12] = {y0.x,y0.y, y1.x,y1.y, y2.x,y2.y,
                              y3.x,y3.y, y4.x,y4.y, y5.x,y5.y};
#pragma unroll
        for (int r = 0; r < 12; ++r)
#pragma unroll
            for (int s = 0; s < 12; ++s) acc[r][s] += xr[r] * yr[s];
    }
    __syncthreads();   // Xl/Ylh dead; red overlays Xl

    // --- phase 3: softmax over rows (fp32; P~ left unnormalized) ---
#pragma unroll
    for (int r = 0; r < 12; ++r) {
        float pm = acc[r][0];
#pragma unroll
        for (int s = 1; s < 12; ++s) pm = fmaxf(pm, acc[r][s]);
        red[(i0 + r)*17 + tj] = pm;
    }
    __syncthreads();
    if (t < 192) {
        float m = red[t*17];
#pragma unroll
        for (int k = 1; k < 16; ++k) m = fmaxf(m, red[t*17 + k]);
        mrow[t] = m;
    }
    __syncthreads();
#pragma unroll
    for (int r = 0; r < 12; ++r) {
        const float mi = mrow[i0 + r];
        float ps = 0.f;
#pragma unroll
        for (int s = 0; s < 12; ++s) {
            acc[r][s] = __expf(acc[r][s] - mi);
            ps += acc[r][s];
        }
        red[(i0 + r)*17 + tj] = ps;
    }
    __syncthreads();
    if (t < 192) {
        float l = 0.f;
#pragma unroll
        for (int k = 0; k < 16; ++k) l += red[t*17 + k];
        lrow[t] = 1.f / l;
    }
    __syncthreads();

    // --- phase 4: store unnormalized P~ as fp16 (overwrites red/Xl region) ---
#pragma unroll
    for (int r = 0; r < 12; ++r) {
        __half2* pr = reinterpret_cast<__half2*>(&Plh[(i0 + r)*SP + j0]);
#pragma unroll
        for (int q = 0; q < 6; ++q)
            pr[q] = __floats2half2_rn(acc[r][2*q], acc[r][2*q+1]);
    }
    __syncthreads();

    // --- phase 5: Z[c][i] = lrow[i] * sum_j U[c][j] P~[i][j];
    //     U streamed from global (L2-hot broadcast), P~ fp16 from LDS. ---
    const int ci = t & 15, ii = t >> 4;
    const int c0z = 4*ci, i0z = 12*ii;
    const float* Ub = U + gbase;
    float accz[4][12];
#pragma unroll
    for (int k = 0; k < 4; ++k)
#pragma unroll
        for (int m = 0; m < 12; ++m) accz[k][m] = 0.f;
#pragma unroll 2
    for (int jq = 0; jq < 48; ++jq) {
        const int j4 = 4*jq;
        float4 u4[4];
#pragma unroll
        for (int k = 0; k < 4; ++k)
            u4[k] = *reinterpret_cast<const float4*>(&Ub[(size_t)(c0z+k)*NPIX + j4]);
        float2 pa[12], pb[12];
#pragma unroll
        for (int m = 0; m < 12; ++m) {
            const __half2* pp = reinterpret_cast<const __half2*>(&Plh[(i0z+m)*SP + j4]);
            pa[m] = __half22float2(pp[0]);
            pb[m] = __half22float2(pp[1]);
        }
#pragma unroll
        for (int k = 0; k < 4; ++k)
#pragma unroll
            for (int m = 0; m < 12; ++m) {
                accz[k][m] += u4[k].x * pa[m].x + u4[k].y * pa[m].y
                            + u4[k].z * pb[m].x + u4[k].w * pb[m].y;
            }
    }
    float lr[12];
#pragma unroll
    for (int m = 0; m < 12; ++m) lr[m] = lrow[i0z + m];
#pragma unroll
    for (int k = 0; k < 4; ++k) {
        float* zr = Z + gbase + (size_t)(c0z + k)*NPIX + i0z;
        float4 o0, o1, o2;
        o0.x = accz[k][0]*lr[0]; o0.y = accz[k][1]*lr[1];  o0.z = accz[k][2]*lr[2];   o0.w = accz[k][3]*lr[3];
        o1.x = accz[k][4]*lr[4]; o1.y = accz[k][5]*lr[5];  o1.z = accz[k][6]*lr[6];   o1.w = accz[k][7]*lr[7];
        o2.x = accz[k][8]*lr[8]; o2.y = accz[k][9]*lr[9];  o2.z = accz[k][10]*lr[10]; o2.w = accz[k][11]*lr[11];
        *reinterpret_cast<float4*>(zr)     = o0;
        *reinterpret_cast<float4*>(zr + 4) = o1;
        *reinterpret_cast<float4*>(zr + 8) = o2;
    }
}

// ---------------------------------------------------------------------------
// HW transpose per image: out[img][x][y] = in[img][y][x]. grid (6,6,B*C).
// ---------------------------------------------------------------------------
__global__ __launch_bounds__(256) void k_transpose(
    const float* __restrict__ in, float* __restrict__ out)
{
    __shared__ float tile[32][33];
    const int tx = threadIdx.x & 31, ty = threadIdx.x >> 5;
    const int x0 = blockIdx.x*32, y0 = blockIdx.y*32;
    const float* img = in + blockIdx.z * NPIX;
    float* og = out + blockIdx.z * NPIX;
#pragma unroll
    for (int r = ty; r < 32; r += 8) tile[r][tx] = img[(y0+r)*WW + x0+tx];
    __syncthreads();
#pragma unroll
    for (int r = ty; r < 32; r += 8) og[(x0+r)*WW + (y0+tx)] = tile[tx][r];
}

// ---------------------------------------------------------------------------
extern "C" void kernel_launch(void* const* d_in, const int* in_sizes, int n_in,
                              void* d_out, int out_size, void* d_ws, size_t ws_size,
                              hipStream_t stream) {
    const float* x       = (const float*)d_in[0];
    const float* pw_w    = (const float*)d_in[1];
    const float* dw_w    = (const float*)d_in[2];
    const float* dw_b    = (const float*)d_in[3];
    const float* conv2_w = (const float*)d_in[4];
    const float* conv2_b = (const float*)d_in[5];
    const float* conv0_w = (const float*)d_in[6];
    const float* conv0_b = (const float*)d_in[7];
    const float* attq    = (const float*)d_in[8];
    const float* attk    = (const float*)d_in[9];
    const float* attv    = (const float*)d_in[10];
    const float* attp    = (const float*)d_in[11];
    const float* temp    = (const float*)d_in[12];
    const float* rq      = (const float*)d_in[13];
    const float* rk      = (const float*)d_in[14];
    const float* rv      = (const float*)d_in[15];
    const float* rg      = (const float*)d_in[16];
    const float* cq      = (const float*)d_in[17];
    const float* ck      = (const float*)d_in[18];
    const float* cv      = (const float*)d_in[19];
    const float* cg      = (const float*)d_in[20];
    const float* fw      = (const float*)d_in[21];
    const float* fb      = (const float*)d_in[22];

    float* ws = (float*)d_ws;
    float* A  = ws;                 // t0 -> x1 (lives to end)
    float* Bf = ws + (size_t)ST;    // g -> out1
    float* Cf = ws + 2*(size_t)ST;  // x1t -> Z2
    float* Df = ws + 3*(size_t)ST;  // out1t -> Z3
    float* Ef = ws + 4*(size_t)ST;  // Z3t -> final pass-1 tmp
    float* partials = ws + 5*(size_t)ST;   // 576*4096 = 2359296 floats
    float* G1 = partials + 576*4096;       // 16384
    float* M2 = G1 + 16384;                // 16384
    float* Wtr  = M2 + 16384;              // 5 x 4096
    float* Wtc  = Wtr + 4096;
    float* Wf2p = Wtc + 4096;
    float* Wf3p = Wf2p + 4096;
    float* Wfx  = Wf3p + 4096;

    const size_t need = ((size_t)5*ST + 576*4096 + 16384 + 16384 + 5*4096)
                        * sizeof(float);
    if (ws_size < need) {
        fprintf(stderr, "kernel_launch: ws_size %zu < needed %zu\n", ws_size, need);
        return;
    }

    (void)hipFuncSetAttribute((const void*)k_gram_part,
        hipFuncAttributeMaxDynamicSharedMemorySize, 69632);
    (void)hipFuncSetAttribute((const void*)k_attn_small,
        hipFuncAttributeMaxDynamicSharedMemorySize, 74240);
    (void)hipFuncSetAttribute((const void*)k_attn_fused,
        hipFuncAttributeMaxDynamicSharedMemorySize, 76032);

    const dim3 blk256(256), blk192(192);
    const dim3 gconv(NPIX/256, BB);      // (144, 4)
    const dim3 gline(HH, BB);            // (192, 4)
    const dim3 gtr(6, 6, BB*C);

    // 0) fold weights
    k_small_mats<<<dim3(5), blk256, 0, stream>>>(rq, rk, cq, ck, fw, rv, cv,
                                                 rg, cg, Wtr, Wtc, Wf2p, Wf3p, Wfx);
    // 1) A = pw_w @ x
    k_conv<false,false,false><<<gconv, blk256, 0, stream>>>(
        x, nullptr, pw_w, nullptr, nullptr, nullptr, nullptr, A, 64, 64);
    // 2) B = gelu(dw3x3(A) + dw_b)
    k_dw<<<dim3(HH, BB*C), blk192, 0, stream>>>(A, dw_w, dw_b, Bf);
    // 3) A = x1 = conv2@B + conv0@x + conv2_b + conv0_b
    k_conv<true,false,false><<<gconv, blk256, 0, stream>>>(
        Bf, x, conv2_w, conv0_w, conv2_b, conv0_b, nullptr, A, 64, 64);
    // 4) channel attention collapse -> M2
    k_gram_part<<<gconv, blk256, 69632, stream>>>(A, partials);
    k_gram_reduce<<<dim3(64), blk256, 0, stream>>>(partials, G1);
    k_attn_small<<<dim3(BB), blk256, 74240, stream>>>(G1, attq, attk, attv, attp, temp, M2);
    // 5) B = out1 = M2[b] @ x1
    k_conv<false,true,false><<<gconv, blk256, 0, stream>>>(
        A, nullptr, M2, nullptr, nullptr, nullptr, nullptr, Bf, 64, 64);
    // 6) C = x1t, D = out1t
    k_transpose<<<gtr, blk256, 0, stream>>>(A, Cf);
    k_transpose<<<gtr, blk256, 0, stream>>>(Bf, Df);
    // 7) col attention fused: E = Z3t
    k_attn_fused<<<gline, blk256, 76032, stream>>>(Cf, Wtc, Df, Ef);
    // 8) D = Z3 = transpose(Z3t)
    k_transpose<<<gtr, blk256, 0, stream>>>(Ef, Df);
    // 9) row attention fused: C = Z2
    k_attn_fused<<<gline, blk256, 76032, stream>>>(A, Wtr, Bf, Cf);
    // 10) final fuse (folded): out = gelu(Wf1@out1 + Wf2p@Z2 + Wf3p@Z3
    //                                      + Wfx@x1 + fb)
    k_conv<true,false,false><<<gconv, blk256, 0, stream>>>(
        Bf, Cf, fw, Wf2p, fb, nullptr, nullptr, Ef, 192, 64);
    k_conv<true,false,true><<<gconv, blk256, 0, stream>>>(
        Df, A, Wf3p, Wfx, nullptr, nullptr, Ef, (float*)d_out, 64, 64);
}

// Round 7
// 987.533 us; speedup vs baseline: 1.2596x; 1.1190x over previous
//
#include <hip/hip_runtime.h>
#include <hip/hip_fp16.h>
#include <cstdio>

#define BB 4
#define C 64
#define HH 192
#define WW 192
#define NPIX (HH*WW)            /* 36864 */
#define ST (BB*C*NPIX)          /* 9437184 floats per tensor */

__device__ __forceinline__ float gelu_f(float v) {
    return 0.5f * v * (1.0f + erff(v * 0.70710678118654752440f));
}

// ---------------------------------------------------------------------------
// Generic 1x1 conv over NCHW: out[b,o,n] = W1@in1 (+ W2@in2) (+bias1)(+bias2)
// (+res)(gelu). grid = (NPIX/128, B), block = 128 (1152 blocks = 4.5/CU;
// the old 256-thr/576-block config left a 33% CU-tail imbalance).
// ---------------------------------------------------------------------------
template<bool TWO_IN, bool PERB, bool DO_GELU>
__global__ __launch_bounds__(128) void k_conv(
    const float* __restrict__ in1, const float* __restrict__ in2,
    const float* __restrict__ W1, const float* __restrict__ W2,
    const float* __restrict__ bias1, const float* __restrict__ bias2,
    const float* __restrict__ res, float* __restrict__ out1,
    int ldw1, int ldw2)
{
    const int n = blockIdx.x * 128 + threadIdx.x;
    const int b = blockIdx.y;
    const int base = b * (C * NPIX) + n;
    float xv[C];
#pragma unroll
    for (int c = 0; c < C; ++c) xv[c] = in1[base + c * NPIX];
    float yv[TWO_IN ? C : 1];
    if (TWO_IN) {
#pragma unroll
        for (int c = 0; c < C; ++c) yv[c] = in2[base + c * NPIX];
    }
    const float* w1 = W1 + (PERB ? b * C * C : 0);
    for (int o = 0; o < C; ++o) {
        const float* wr = w1 + o * ldw1;
        float a0 = 0.f, a1 = 0.f, a2 = 0.f, a3 = 0.f;
#pragma unroll
        for (int c = 0; c < C; c += 4) {
            a0 += wr[c+0] * xv[c+0];
            a1 += wr[c+1] * xv[c+1];
            a2 += wr[c+2] * xv[c+2];
            a3 += wr[c+3] * xv[c+3];
        }
        if (TWO_IN) {
            const float* wr2 = W2 + o * ldw2;
#pragma unroll
            for (int c = 0; c < C; c += 4) {
                a0 += wr2[c+0] * yv[c+0];
                a1 += wr2[c+1] * yv[c+1];
                a2 += wr2[c+2] * yv[c+2];
                a3 += wr2[c+3] * yv[c+3];
            }
        }
        float acc = (a0 + a1) + (a2 + a3);
        if (bias1) acc += bias1[o];
        if (bias2) acc += bias2[o];
        const int ob = base + o * NPIX;
        if (res) acc += res[ob];
        if (DO_GELU) acc = gelu_f(acc);
        out1[ob] = acc;
    }
}

// ---------------------------------------------------------------------------
// FUSED final conv: out = gelu(W1@i1 + W2@i2 + W3@i3 + W4@i4 + bias).
// GEMM-style: 64(o) x 128(px) tile per block, 256 threads, acc[8][4]/thread
// (compile-time indexed, no scratch). LDS: Wl[64][68] (W^T, 17408 B) +
// Xl[64][132] (33792 B) = 51200 B -> 3 blocks/CU. Inputs staged one at a
// time through the same LDS -> no 256-VGPR blowup, no Ef HBM round-trip
// (saves 75 MB/iter + one dispatch vs the old 10a/10b pair).
// ---------------------------------------------------------------------------
__global__ __launch_bounds__(256, 3) void k_conv4(
    const float* __restrict__ i1, const float* __restrict__ i2,
    const float* __restrict__ i3, const float* __restrict__ i4,
    const float* __restrict__ W1, const float* __restrict__ W2,
    const float* __restrict__ W3, const float* __restrict__ W4,
    const float* __restrict__ bias, float* __restrict__ out)
{
    extern __shared__ float sm[];
    float* Wl = sm;            // [64][68]  Wl[c][o] = W[o][c]
    float* Xl = sm + 4352;     // [64][132] Xl[c][p]
    const int t = threadIdx.x;
    const int px0 = blockIdx.x * 128;
    const int b = blockIdx.y;
    const size_t base = (size_t)b*(C*NPIX) + px0;
    const int to = t >> 5, tp = t & 31;
    const int o0 = to*8, p0 = tp*4;
    float acc[8][4];
#pragma unroll
    for (int k = 0; k < 8; ++k) {
        const float bo = bias[o0+k];
#pragma unroll
        for (int m = 0; m < 4; ++m) acc[k][m] = bo;
    }
#pragma unroll
    for (int inp = 0; inp < 4; ++inp) {
        const float* In = (inp==0)?i1:(inp==1)?i2:(inp==2)?i3:i4;
        const float* Wk = (inp==0)?W1:(inp==1)?W2:(inp==2)?W3:W4;
        const int ldw = (inp==0)?192:64;
        // stage W^T (4096 elems, coalesced global reads along c)
#pragma unroll
        for (int k = 0; k < 16; ++k) {
            const int idx = k*256 + t;
            const int o = idx >> 6, c = idx & 63;
            Wl[c*68 + o] = Wk[o*ldw + c];
        }
        // stage input tile (8192 floats as float4, coalesced)
#pragma unroll
        for (int k = 0; k < 8; ++k) {
            const int f4 = k*256 + t;
            const int c = f4 >> 5, p4 = (f4 & 31)*4;
            *reinterpret_cast<float4*>(&Xl[c*132 + p4]) =
                *reinterpret_cast<const float4*>(&In[base + (size_t)c*NPIX + p4]);
        }
        __syncthreads();
#pragma unroll 2
        for (int c = 0; c < 64; ++c) {
            const float4 wa = *reinterpret_cast<const float4*>(&Wl[c*68 + o0]);
            const float4 wb = *reinterpret_cast<const float4*>(&Wl[c*68 + o0 + 4]);
            const float4 xv = *reinterpret_cast<const float4*>(&Xl[c*132 + p0]);
            const float wr[8] = {wa.x,wa.y,wa.z,wa.w, wb.x,wb.y,wb.z,wb.w};
            const float xr[4] = {xv.x,xv.y,xv.z,xv.w};
#pragma unroll
            for (int k = 0; k < 8; ++k)
#pragma unroll
                for (int m = 0; m < 4; ++m) acc[k][m] += wr[k]*xr[m];
        }
        __syncthreads();
    }
#pragma unroll
    for (int k = 0; k < 8; ++k) {
        float4 o4;
        o4.x = gelu_f(acc[k][0]); o4.y = gelu_f(acc[k][1]);
        o4.z = gelu_f(acc[k][2]); o4.w = gelu_f(acc[k][3]);
        *reinterpret_cast<float4*>(&out[base + (size_t)(o0+k)*NPIX + p0]) = o4;
    }
}

// ---------------------------------------------------------------------------
// Depthwise 3x3 (pad 1) + bias + GELU.  grid = (H, B*C), block = 192 (=W).
// ---------------------------------------------------------------------------
__global__ __launch_bounds__(192) void k_dw(
    const float* __restrict__ t0, const float* __restrict__ w,
    const float* __restrict__ bias, float* __restrict__ g)
{
    const int x = threadIdx.x;
    const int y = blockIdx.x;
    const int bc = blockIdx.y;
    const int c = bc & 63;
    const float* img = t0 + bc * NPIX;
    const float* wc = w + c * 9;
    float acc = bias[c];
#pragma unroll
    for (int dy = -1; dy <= 1; ++dy) {
        const int yy = y + dy;
        if (yy < 0 || yy > 191) continue;
#pragma unroll
        for (int dx = -1; dx <= 1; ++dx) {
            const int xx = x + dx;
            if (xx < 0 || xx > 191) continue;
            acc += img[yy*WW + xx] * wc[(dy+1)*3 + (dx+1)];
        }
    }
    g[bc*NPIX + y*WW + x] = gelu_f(acc);
}

// ---------------------------------------------------------------------------
// Per-batch Gram G1 = X1 * X1^T: partial per 256-pixel chunk.
// ---------------------------------------------------------------------------
__global__ __launch_bounds__(256) void k_gram_part(
    const float* __restrict__ x1p, float* __restrict__ part)
{
    extern __shared__ float lt[];     // [256][68]
    const int chunk = blockIdx.x, b = blockIdx.y, t = threadIdx.x;
    const int gbase = b * (C*NPIX) + chunk * 256;
    for (int idx = t; idx < C*256; idx += 256) {
        const int c = idx >> 8, n = idx & 255;
        lt[n*68 + c] = x1p[gbase + c*NPIX + n];
    }
    __syncthreads();
    const int ti = t & 15, tj = t >> 4;
    float acc[4][4];
#pragma unroll
    for (int r = 0; r < 4; ++r)
#pragma unroll
        for (int s = 0; s < 4; ++s) acc[r][s] = 0.f;
    for (int n = 0; n < 256; ++n) {
        const float4 av = *reinterpret_cast<const float4*>(&lt[n*68 + 4*ti]);
        const float4 bv = *reinterpret_cast<const float4*>(&lt[n*68 + 4*tj]);
        const float ar[4] = {av.x, av.y, av.z, av.w};
        const float br[4] = {bv.x, bv.y, bv.z, bv.w};
#pragma unroll
        for (int r = 0; r < 4; ++r)
#pragma unroll
            for (int s = 0; s < 4; ++s) acc[r][s] += ar[r] * br[s];
    }
    float* pb = part + (b*144 + chunk)*4096;
#pragma unroll
    for (int r = 0; r < 4; ++r)
#pragma unroll
        for (int s = 0; s < 4; ++s) pb[(4*ti+r)*64 + (4*tj+s)] = acc[r][s];
}

__global__ __launch_bounds__(256) void k_gram_reduce(
    const float* __restrict__ part, float* __restrict__ G1)
{
    const int flat = blockIdx.x*256 + threadIdx.x;   // < 16384
    const int b = flat >> 12, ij = flat & 4095;
    float s = 0.f;
    for (int ch = 0; ch < 144; ++ch) s += part[(b*144+ch)*4096 + ij];
    G1[flat] = s;
}

// ---------------------------------------------------------------------------
// Channel-attention collapse: per batch, M2 = Wp * blockdiag(attn) * Wv.
// ---------------------------------------------------------------------------
__global__ __launch_bounds__(256) void k_attn_small(
    const float* __restrict__ G1a, const float* __restrict__ Wq,
    const float* __restrict__ Wk, const float* __restrict__ Wv,
    const float* __restrict__ Wp, const float* __restrict__ temp,
    float* __restrict__ M2)
{
    extern __shared__ float sm[];
    float* g1 = sm;
    float* wa = sm + 4096;
    float* wb = sm + 8192;
    float* u  = sm + 12288;
    float* at = sm + 16384;
    float* nq = sm + 18432;
    float* nk = sm + 18496;
    const int b = blockIdx.x, t = threadIdx.x;
    const float* G = G1a + b*4096;
    for (int i = t; i < 4096; i += 256) { g1[i] = G[i]; wa[i] = Wq[i]; wb[i] = Wk[i]; }
    __syncthreads();
    {
        const int r = t >> 2, q4 = t & 3;
        for (int cc = q4*16; cc < q4*16 + 16; ++cc) {
            float s = 0.f;
            for (int k = 0; k < 64; ++k) s += wa[r*64+k] * g1[k*64+cc];
            u[r*64+cc] = s;
        }
    }
    __syncthreads();
    {
        const int d = t >> 2, kq = t & 3;
        float p = 0.f;
        for (int k = kq*16; k < kq*16 + 16; ++k) {
            float tk = 0.f;
            for (int c2 = 0; c2 < 64; ++c2) tk += g1[k*64+c2] * wb[d*64+c2];
            p += wb[d*64+k] * tk;
        }
        p += __shfl_xor(p, 1);
        p += __shfl_xor(p, 2);
        if (kq == 0) nk[d] = sqrtf(fmaxf(p, 0.f));
    }
    if (t < 64) {
        float s = 0.f;
        for (int c2 = 0; c2 < 64; ++c2) s += u[t*64+c2] * wa[t*64+c2];
        nq[t] = sqrtf(fmaxf(s, 0.f));
    }
    __syncthreads();
    if (t < 64) {
        const int gI = t >> 5;
        const float tg = temp[gI];
        const float dq = fmaxf(nq[t], 1e-12f);
        float row[32];
        float mx = -1e30f;
#pragma unroll
        for (int d2 = 0; d2 < 32; ++d2) {
            const int dd = gI*32 + d2;
            float s = 0.f;
            for (int c2 = 0; c2 < 64; ++c2) s += u[t*64+c2] * wb[dd*64+c2];
            s = s * tg / (dq * fmaxf(nk[dd], 1e-12f));
            row[d2] = s; mx = fmaxf(mx, s);
        }
        float se = 0.f;
#pragma unroll
        for (int d2 = 0; d2 < 32; ++d2) { row[d2] = __expf(row[d2]-mx); se += row[d2]; }
        const float inv = 1.f / se;
#pragma unroll
        for (int d2 = 0; d2 < 32; ++d2) at[t*32+d2] = row[d2]*inv;
    }
    __syncthreads();
    for (int i = t; i < 4096; i += 256) { wa[i] = Wv[i]; wb[i] = Wp[i]; }
    __syncthreads();
    {
        const int m = t >> 2, q4 = t & 3, gI = m >> 5;
        for (int e = q4*16; e < q4*16 + 16; ++e) {
            float s = 0.f;
#pragma unroll
            for (int d2 = 0; d2 < 32; ++d2) s += at[m*32+d2] * wa[(gI*32+d2)*64 + e];
            g1[m*64+e] = s;
        }
    }
    __syncthreads();
    {
        const int o = t >> 2, q4 = t & 3;
        for (int e = q4*16; e < q4*16 + 16; ++e) {
            float s = 0.f;
            for (int m = 0; m < 64; ++m) s += wb[o*64+m] * g1[m*64+e];
            M2[b*4096 + o*64+e] = s;
        }
    }
}

// ---------------------------------------------------------------------------
// Small weight-folding products:
//  0: Wtr = rq^T rk   1: Wtc = cq^T ck
//  2: Wf2p = gr * Wf[:,64:128] @ rv   3: Wf3p = gc * Wf[:,128:192] @ cv
//  4: Wfx  = Wf[:,64:128] + Wf[:,128:192]
// ---------------------------------------------------------------------------
__global__ __launch_bounds__(256) void k_small_mats(
    const float* __restrict__ rq, const float* __restrict__ rk,
    const float* __restrict__ cq, const float* __restrict__ ck,
    const float* __restrict__ fw, const float* __restrict__ rv,
    const float* __restrict__ cv, const float* __restrict__ rg,
    const float* __restrict__ cg,
    float* __restrict__ Wtr, float* __restrict__ Wtc,
    float* __restrict__ Wf2p, float* __restrict__ Wf3p,
    float* __restrict__ Wfx)
{
    const int which = blockIdx.x, t = threadIdx.x;
    const int a = t >> 2, b0 = (t & 3) * 16;
    if (which <= 1) {
        const float* Q = which ? cq : rq;
        const float* Kw = which ? ck : rk;
        float* O = which ? Wtc : Wtr;
        for (int b = b0; b < b0 + 16; ++b) {
            float s = 0.f;
            for (int co = 0; co < 64; ++co) s += Q[co*64 + a] * Kw[co*64 + b];
            O[a*64 + b] = s;
        }
    } else if (which <= 3) {
        const float* Vw = (which == 2) ? rv : cv;
        const float g = (which == 2) ? rg[0] : cg[0];
        const int off = (which == 2) ? 64 : 128;
        float* O = (which == 2) ? Wf2p : Wf3p;
        for (int b = b0; b < b0 + 16; ++b) {
            float s = 0.f;
            for (int m = 0; m < 64; ++m) s += fw[a*192 + off + m] * Vw[m*64 + b];
            O[a*64 + b] = g * s;
        }
    } else {
        for (int b = b0; b < b0 + 16; ++b)
            Wfx[a*64 + b] = fw[a*192 + 64 + b] + fw[a*192 + 128 + b];
    }
}

// ---------------------------------------------------------------------------
// FUSED per-line attention, 2 blocks/CU via fp16 LDS intermediates.
//   Y = Wt @ X   (fp32 math, stored fp16 in LDS; Wt read from global/L2)
//   S = X^T Y    (fp32 12x12 register tiles)
//   P~ = exp(S - rowmax) stored fp16 (unnormalized); 1/l kept in lrow (fp32)
//   Z[c][i] = (1/l_i) * sum_j U[c][j] P~[i][j]  (U streamed from global/L2)
// grid (192, B), block = 256.  dyn LDS = 76032 B -> 2 blocks/CU.
// (R6 verified: occ 11->18%, VALUBusy 50->65%, 176->150 us.)
// ---------------------------------------------------------------------------
#define SP 196
__global__ __launch_bounds__(256, 2) void k_attn_fused(
    const float* __restrict__ X, const float* __restrict__ Wt,
    const float* __restrict__ U, float* __restrict__ Z)
{
    extern __shared__ float sm[];
    float* Xl = sm;                                   // [64][196] fp32
    __half* Ylh = reinterpret_cast<__half*>(sm + 12544);  // [64][196] fp16
    __half* Plh = reinterpret_cast<__half*>(sm);      // [192][196] fp16 overlay
    float* red  = sm;                                 // [192][17] overlay (ph3)
    float* mrow = sm + 3264;                          // 192 (in dead Xl)
    float* lrow = sm + 18816;                         // 192, persistent @75264B
    const int t = threadIdx.x;
    const int h = blockIdx.x, b = blockIdx.y;
    const size_t gbase = (size_t)b*(C*NPIX) + (size_t)h*WW;

    // --- phase 0: load X line ---
#pragma unroll 4
    for (int k = 0; k < 48; ++k) {
        const int idx = k*256 + t;
        const int c = idx / 192, j = idx - c*192;
        Xl[c*SP + j] = X[gbase + (size_t)c*NPIX + j];
    }
    __syncthreads();

    // --- phase 1: Y = Wt @ X (fp32 math), store fp16. Wt from global. ---
    {
        const int tc = t & 15, tjy = t >> 4;
        const int c0 = 4*tc, j0y = 12*tjy;
        float accy[4][12];
#pragma unroll
        for (int k = 0; k < 4; ++k)
#pragma unroll
            for (int m = 0; m < 12; ++m) accy[k][m] = 0.f;
        for (int a = 0; a < 64; ++a) {
            const float4 w4 = *reinterpret_cast<const float4*>(&Wt[a*64 + c0]);
            const float4 xa = *reinterpret_cast<const float4*>(&Xl[a*SP + j0y]);
            const float4 xb = *reinterpret_cast<const float4*>(&Xl[a*SP + j0y + 4]);
            const float4 xc = *reinterpret_cast<const float4*>(&Xl[a*SP + j0y + 8]);
            const float wr[4]  = {w4.x, w4.y, w4.z, w4.w};
            const float xr[12] = {xa.x,xa.y,xa.z,xa.w, xb.x,xb.y,xb.z,xb.w,
                                  xc.x,xc.y,xc.z,xc.w};
#pragma unroll
            for (int k = 0; k < 4; ++k)
#pragma unroll
                for (int m = 0; m < 12; ++m) accy[k][m] += wr[k] * xr[m];
        }
#pragma unroll
        for (int k = 0; k < 4; ++k) {
            __half2* yr = reinterpret_cast<__half2*>(&Ylh[(c0+k)*SP + j0y]);
#pragma unroll
            for (int q = 0; q < 6; ++q)
                yr[q] = __floats2half2_rn(accy[k][2*q], accy[k][2*q+1]);
        }
    }
    __syncthreads();

    // --- phase 2: S = X^T Y, fp32 12x12 per thread (Y converted on read) ---
    const int ti = t & 15, tj = t >> 4;
    const int i0 = ti*12, j0 = tj*12;
    float acc[12][12];
#pragma unroll
    for (int r = 0; r < 12; ++r)
#pragma unroll
        for (int s = 0; s < 12; ++s) acc[r][s] = 0.f;
#pragma unroll 2
    for (int c = 0; c < 64; ++c) {
        const float4 xa = *reinterpret_cast<const float4*>(&Xl[c*SP + i0]);
        const float4 xb = *reinterpret_cast<const float4*>(&Xl[c*SP + i0 + 4]);
        const float4 xc = *reinterpret_cast<const float4*>(&Xl[c*SP + i0 + 8]);
        const __half2* yp = reinterpret_cast<const __half2*>(&Ylh[c*SP + j0]);
        const float2 y0 = __half22float2(yp[0]);
        const float2 y1 = __half22float2(yp[1]);
        const float2 y2 = __half22float2(yp[2]);
        const float2 y3 = __half22float2(yp[3]);
        const float2 y4 = __half22float2(yp[4]);
        const float2 y5 = __half22float2(yp[5]);
        const float xr[12] = {xa.x,xa.y,xa.z,xa.w, xb.x,xb.y,xb.z,xb.w, xc.x,xc.y,xc.z,xc.w};
        const float yr[12] = {y0.x,y0.y, y1.x,y1.y, y2.x,y2.y,
                              y3.x,y3.y, y4.x,y4.y, y5.x,y5.y};
#pragma unroll
        for (int r = 0; r < 12; ++r)
#pragma unroll
            for (int s = 0; s < 12; ++s) acc[r][s] += xr[r] * yr[s];
    }
    __syncthreads();   // Xl/Ylh dead; red overlays Xl

    // --- phase 3: softmax over rows (fp32; P~ left unnormalized) ---
#pragma unroll
    for (int r = 0; r < 12; ++r) {
        float pm = acc[r][0];
#pragma unroll
        for (int s = 1; s < 12; ++s) pm = fmaxf(pm, acc[r][s]);
        red[(i0 + r)*17 + tj] = pm;
    }
    __syncthreads();
    if (t < 192) {
        float m = red[t*17];
#pragma unroll
        for (int k = 1; k < 16; ++k) m = fmaxf(m, red[t*17 + k]);
        mrow[t] = m;
    }
    __syncthreads();
#pragma unroll
    for (int r = 0; r < 12; ++r) {
        const float mi = mrow[i0 + r];
        float ps = 0.f;
#pragma unroll
        for (int s = 0; s < 12; ++s) {
            acc[r][s] = __expf(acc[r][s] - mi);
            ps += acc[r][s];
        }
        red[(i0 + r)*17 + tj] = ps;
    }
    __syncthreads();
    if (t < 192) {
        float l = 0.f;
#pragma unroll
        for (int k = 0; k < 16; ++k) l += red[t*17 + k];
        lrow[t] = 1.f / l;
    }
    __syncthreads();

    // --- phase 4: store unnormalized P~ as fp16 (overwrites red/Xl region) ---
#pragma unroll
    for (int r = 0; r < 12; ++r) {
        __half2* pr = reinterpret_cast<__half2*>(&Plh[(i0 + r)*SP + j0]);
#pragma unroll
        for (int q = 0; q < 6; ++q)
            pr[q] = __floats2half2_rn(acc[r][2*q], acc[r][2*q+1]);
    }
    __syncthreads();

    // --- phase 5: Z[c][i] = lrow[i] * sum_j U[c][j] P~[i][j];
    //     U streamed from global (L2-hot broadcast), P~ fp16 from LDS. ---
    const int ci = t & 15, ii = t >> 4;
    const int c0z = 4*ci, i0z = 12*ii;
    const float* Ub = U + gbase;
    float accz[4][12];
#pragma unroll
    for (int k = 0; k < 4; ++k)
#pragma unroll
        for (int m = 0; m < 12; ++m) accz[k][m] = 0.f;
#pragma unroll 2
    for (int jq = 0; jq < 48; ++jq) {
        const int j4 = 4*jq;
        float4 u4[4];
#pragma unroll
        for (int k = 0; k < 4; ++k)
            u4[k] = *reinterpret_cast<const float4*>(&Ub[(size_t)(c0z+k)*NPIX + j4]);
        float2 pa[12], pb[12];
#pragma unroll
        for (int m = 0; m < 12; ++m) {
            const __half2* pp = reinterpret_cast<const __half2*>(&Plh[(i0z+m)*SP + j4]);
            pa[m] = __half22float2(pp[0]);
            pb[m] = __half22float2(pp[1]);
        }
#pragma unroll
        for (int k = 0; k < 4; ++k)
#pragma unroll
            for (int m = 0; m < 12; ++m) {
                accz[k][m] += u4[k].x * pa[m].x + u4[k].y * pa[m].y
                            + u4[k].z * pb[m].x + u4[k].w * pb[m].y;
            }
    }
    float lr[12];
#pragma unroll
    for (int m = 0; m < 12; ++m) lr[m] = lrow[i0z + m];
#pragma unroll
    for (int k = 0; k < 4; ++k) {
        float* zr = Z + gbase + (size_t)(c0z + k)*NPIX + i0z;
        float4 o0, o1, o2;
        o0.x = accz[k][0]*lr[0]; o0.y = accz[k][1]*lr[1];  o0.z = accz[k][2]*lr[2];   o0.w = accz[k][3]*lr[3];
        o1.x = accz[k][4]*lr[4]; o1.y = accz[k][5]*lr[5];  o1.z = accz[k][6]*lr[6];   o1.w = accz[k][7]*lr[7];
        o2.x = accz[k][8]*lr[8]; o2.y = accz[k][9]*lr[9];  o2.z = accz[k][10]*lr[10]; o2.w = accz[k][11]*lr[11];
        *reinterpret_cast<float4*>(zr)     = o0;
        *reinterpret_cast<float4*>(zr + 4) = o1;
        *reinterpret_cast<float4*>(zr + 8) = o2;
    }
}

// ---------------------------------------------------------------------------
// HW transpose per image: out[img][x][y] = in[img][y][x]. grid (6,6,B*C).
// ---------------------------------------------------------------------------
__global__ __launch_bounds__(256) void k_transpose(
    const float* __restrict__ in, float* __restrict__ out)
{
    __shared__ float tile[32][33];
    const int tx = threadIdx.x & 31, ty = threadIdx.x >> 5;
    const int x0 = blockIdx.x*32, y0 = blockIdx.y*32;
    const float* img = in + blockIdx.z * NPIX;
    float* og = out + blockIdx.z * NPIX;
#pragma unroll
    for (int r = ty; r < 32; r += 8) tile[r][tx] = img[(y0+r)*WW + x0+tx];
    __syncthreads();
#pragma unroll
    for (int r = ty; r < 32; r += 8) og[(x0+r)*WW + (y0+tx)] = tile[tx][r];
}

// ---------------------------------------------------------------------------
extern "C" void kernel_launch(void* const* d_in, const int* in_sizes, int n_in,
                              void* d_out, int out_size, void* d_ws, size_t ws_size,
                              hipStream_t stream) {
    const float* x       = (const float*)d_in[0];
    const float* pw_w    = (const float*)d_in[1];
    const float* dw_w    = (const float*)d_in[2];
    const float* dw_b    = (const float*)d_in[3];
    const float* conv2_w = (const float*)d_in[4];
    const float* conv2_b = (const float*)d_in[5];
    const float* conv0_w = (const float*)d_in[6];
    const float* conv0_b = (const float*)d_in[7];
    const float* attq    = (const float*)d_in[8];
    const float* attk    = (const float*)d_in[9];
    const float* attv    = (const float*)d_in[10];
    const float* attp    = (const float*)d_in[11];
    const float* temp    = (const float*)d_in[12];
    const float* rq      = (const float*)d_in[13];
    const float* rk      = (const float*)d_in[14];
    const float* rv      = (const float*)d_in[15];
    const float* rg      = (const float*)d_in[16];
    const float* cq      = (const float*)d_in[17];
    const float* ck      = (const float*)d_in[18];
    const float* cv      = (const float*)d_in[19];
    const float* cg      = (const float*)d_in[20];
    const float* fw      = (const float*)d_in[21];
    const float* fb      = (const float*)d_in[22];

    float* ws = (float*)d_ws;
    float* A  = ws;                 // t0 -> x1 (lives to end)
    float* Bf = ws + (size_t)ST;    // g -> out1
    float* Cf = ws + 2*(size_t)ST;  // x1t -> Z2
    float* Df = ws + 3*(size_t)ST;  // out1t -> Z3
    float* Ef = ws + 4*(size_t)ST;  // Z3t
    float* partials = ws + 5*(size_t)ST;   // 576*4096 = 2359296 floats
    float* G1 = partials + 576*4096;       // 16384
    float* M2 = G1 + 16384;                // 16384
    float* Wtr  = M2 + 16384;              // 5 x 4096
    float* Wtc  = Wtr + 4096;
    float* Wf2p = Wtc + 4096;
    float* Wf3p = Wf2p + 4096;
    float* Wfx  = Wf3p + 4096;

    const size_t need = ((size_t)5*ST + 576*4096 + 16384 + 16384 + 5*4096)
                        * sizeof(float);
    if (ws_size < need) {
        fprintf(stderr, "kernel_launch: ws_size %zu < needed %zu\n", ws_size, need);
        return;
    }

    (void)hipFuncSetAttribute((const void*)k_gram_part,
        hipFuncAttributeMaxDynamicSharedMemorySize, 69632);
    (void)hipFuncSetAttribute((const void*)k_attn_small,
        hipFuncAttributeMaxDynamicSharedMemorySize, 74240);
    (void)hipFuncSetAttribute((const void*)k_attn_fused,
        hipFuncAttributeMaxDynamicSharedMemorySize, 76032);

    const dim3 blk256(256), blk192(192), blk128(128);
    const dim3 gconv(NPIX/128, BB);      // (288, 4): 128-thr conv blocks
    const dim3 ggram(NPIX/256, BB);      // (144, 4): gram chunks stay 256
    const dim3 gline(HH, BB);            // (192, 4)
    const dim3 gtr(6, 6, BB*C);

    // 0) fold weights
    k_small_mats<<<dim3(5), blk256, 0, stream>>>(rq, rk, cq, ck, fw, rv, cv,
                                                 rg, cg, Wtr, Wtc, Wf2p, Wf3p, Wfx);
    // 1) A = pw_w @ x
    k_conv<false,false,false><<<gconv, blk128, 0, stream>>>(
        x, nullptr, pw_w, nullptr, nullptr, nullptr, nullptr, A, 64, 64);
    // 2) B = gelu(dw3x3(A) + dw_b)
    k_dw<<<dim3(HH, BB*C), blk192, 0, stream>>>(A, dw_w, dw_b, Bf);
    // 3) A = x1 = conv2@B + conv0@x + conv2_b + conv0_b
    k_conv<true,false,false><<<gconv, blk128, 0, stream>>>(
        Bf, x, conv2_w, conv0_w, conv2_b, conv0_b, nullptr, A, 64, 64);
    // 4) channel attention collapse -> M2
    k_gram_part<<<ggram, blk256, 69632, stream>>>(A, partials);
    k_gram_reduce<<<dim3(64), blk256, 0, stream>>>(partials, G1);
    k_attn_small<<<dim3(BB), blk256, 74240, stream>>>(G1, attq, attk, attv, attp, temp, M2);
    // 5) B = out1 = M2[b] @ x1
    k_conv<false,true,false><<<gconv, blk128, 0, stream>>>(
        A, nullptr, M2, nullptr, nullptr, nullptr, nullptr, Bf, 64, 64);
    // 6) C = x1t, D = out1t
    k_transpose<<<gtr, blk256, 0, stream>>>(A, Cf);
    k_transpose<<<gtr, blk256, 0, stream>>>(Bf, Df);
    // 7) col attention fused: E = Z3t
    k_attn_fused<<<gline, blk256, 76032, stream>>>(Cf, Wtc, Df, Ef);
    // 8) D = Z3 = transpose(Z3t)
    k_transpose<<<gtr, blk256, 0, stream>>>(Ef, Df);
    // 9) row attention fused: C = Z2
    k_attn_fused<<<gline, blk256, 76032, stream>>>(A, Wtr, Bf, Cf);
    // 10) FUSED final conv: out = gelu(fw[:,0:64]@out1 + Wf2p@Z2 + Wf3p@Z3
    //                                   + Wfx@x1 + fb)  (one kernel, no Ef)
    k_conv4<<<gconv, blk256, 51200, stream>>>(
        Bf, Cf, Df, A, fw, Wf2p, Wf3p, Wfx, fb, (float*)d_out);
}

// Round 8
// 841.223 us; speedup vs baseline: 1.4787x; 1.1739x over previous
//
#include <hip/hip_runtime.h>
#include <hip/hip_fp16.h>
#include <cstdio>

#define BB 4
#define C 64
#define HH 192
#define WW 192
#define NPIX (HH*WW)            /* 36864 */
#define ST (BB*C*NPIX)          /* 9437184 floats per tensor */

__device__ __forceinline__ float gelu_f(float v) {
    return 0.5f * v * (1.0f + erff(v * 0.70710678118654752440f));
}

// ---------------------------------------------------------------------------
// GEMM-style 1x1 conv (replaces scalar k_conv: that pattern held xv[64] in
// VGPRs -> 1-2 waves/SIMD, latency-bound, ~4x off roofline per R7 evidence).
// 64(o) x 128(px) tile per block, 256 thr, acc[8][4]/thread. LDS: Wl[64][68]
// (W^T) + Xl[64][132] = 51200 B -> 3 blocks/CU = 12 waves. Inputs staged
// sequentially through the same LDS (TWO_IN).
// ---------------------------------------------------------------------------
template<bool TWO_IN, bool PERB, bool DO_GELU>
__global__ __launch_bounds__(256, 3) void k_gconv(
    const float* __restrict__ in1, const float* __restrict__ in2,
    const float* __restrict__ W1, const float* __restrict__ W2,
    const float* __restrict__ bias1, const float* __restrict__ bias2,
    float* __restrict__ out, int ldw1, int ldw2)
{
    extern __shared__ float sm[];
    float* Wl = sm;            // [64][68]  Wl[c][o] = W[o][c]
    float* Xl = sm + 4352;     // [64][132] Xl[c][p]
    const int t = threadIdx.x;
    const int px0 = blockIdx.x * 128;
    const int b = blockIdx.y;
    const size_t base = (size_t)b*(C*NPIX) + px0;
    const int to = t >> 5, tp = t & 31;
    const int o0 = to*8, p0 = tp*4;
    float acc[8][4];
#pragma unroll
    for (int k = 0; k < 8; ++k) {
        float bo = 0.f;
        if (bias1) bo += bias1[o0+k];
        if (bias2) bo += bias2[o0+k];
#pragma unroll
        for (int m = 0; m < 4; ++m) acc[k][m] = bo;
    }
    const int NIN = TWO_IN ? 2 : 1;
#pragma unroll
    for (int inp = 0; inp < NIN; ++inp) {
        const float* In = inp ? in2 : in1;
        const float* Wk = inp ? W2 : (PERB ? W1 + b*4096 : W1);
        const int ldw = inp ? ldw2 : ldw1;
        // stage W^T (coalesced along c)
#pragma unroll
        for (int k = 0; k < 16; ++k) {
            const int idx = k*256 + t;
            const int o = idx >> 6, c = idx & 63;
            Wl[c*68 + o] = Wk[o*ldw + c];
        }
        // stage input tile (float4, coalesced)
#pragma unroll
        for (int k = 0; k < 8; ++k) {
            const int f4 = k*256 + t;
            const int c = f4 >> 5, p4 = (f4 & 31)*4;
            *reinterpret_cast<float4*>(&Xl[c*132 + p4]) =
                *reinterpret_cast<const float4*>(&In[base + (size_t)c*NPIX + p4]);
        }
        __syncthreads();
#pragma unroll 2
        for (int c = 0; c < 64; ++c) {
            const float4 wa = *reinterpret_cast<const float4*>(&Wl[c*68 + o0]);
            const float4 wb = *reinterpret_cast<const float4*>(&Wl[c*68 + o0 + 4]);
            const float4 xv = *reinterpret_cast<const float4*>(&Xl[c*132 + p0]);
            const float wr[8] = {wa.x,wa.y,wa.z,wa.w, wb.x,wb.y,wb.z,wb.w};
            const float xr[4] = {xv.x,xv.y,xv.z,xv.w};
#pragma unroll
            for (int k = 0; k < 8; ++k)
#pragma unroll
                for (int m = 0; m < 4; ++m) acc[k][m] += wr[k]*xr[m];
        }
        __syncthreads();
    }
#pragma unroll
    for (int k = 0; k < 8; ++k) {
        float4 o4;
        if (DO_GELU) {
            o4.x = gelu_f(acc[k][0]); o4.y = gelu_f(acc[k][1]);
            o4.z = gelu_f(acc[k][2]); o4.w = gelu_f(acc[k][3]);
        } else {
            o4.x = acc[k][0]; o4.y = acc[k][1];
            o4.z = acc[k][2]; o4.w = acc[k][3];
        }
        *reinterpret_cast<float4*>(&out[base + (size_t)(o0+k)*NPIX + p0]) = o4;
    }
}

// ---------------------------------------------------------------------------
// FUSED final conv: out = gelu(W1@i1 + W2@i2 + W3@i3 + W4@i4 + bias).
// Same tile geometry as k_gconv; validated R7 (saved 118 us vs 2-pass).
// ---------------------------------------------------------------------------
__global__ __launch_bounds__(256, 3) void k_conv4(
    const float* __restrict__ i1, const float* __restrict__ i2,
    const float* __restrict__ i3, const float* __restrict__ i4,
    const float* __restrict__ W1, const float* __restrict__ W2,
    const float* __restrict__ W3, const float* __restrict__ W4,
    const float* __restrict__ bias, float* __restrict__ out)
{
    extern __shared__ float sm[];
    float* Wl = sm;            // [64][68]
    float* Xl = sm + 4352;     // [64][132]
    const int t = threadIdx.x;
    const int px0 = blockIdx.x * 128;
    const int b = blockIdx.y;
    const size_t base = (size_t)b*(C*NPIX) + px0;
    const int to = t >> 5, tp = t & 31;
    const int o0 = to*8, p0 = tp*4;
    float acc[8][4];
#pragma unroll
    for (int k = 0; k < 8; ++k) {
        const float bo = bias[o0+k];
#pragma unroll
        for (int m = 0; m < 4; ++m) acc[k][m] = bo;
    }
#pragma unroll
    for (int inp = 0; inp < 4; ++inp) {
        const float* In = (inp==0)?i1:(inp==1)?i2:(inp==2)?i3:i4;
        const float* Wk = (inp==0)?W1:(inp==1)?W2:(inp==2)?W3:W4;
        const int ldw = (inp==0)?192:64;
#pragma unroll
        for (int k = 0; k < 16; ++k) {
            const int idx = k*256 + t;
            const int o = idx >> 6, c = idx & 63;
            Wl[c*68 + o] = Wk[o*ldw + c];
        }
#pragma unroll
        for (int k = 0; k < 8; ++k) {
            const int f4 = k*256 + t;
            const int c = f4 >> 5, p4 = (f4 & 31)*4;
            *reinterpret_cast<float4*>(&Xl[c*132 + p4]) =
                *reinterpret_cast<const float4*>(&In[base + (size_t)c*NPIX + p4]);
        }
        __syncthreads();
#pragma unroll 2
        for (int c = 0; c < 64; ++c) {
            const float4 wa = *reinterpret_cast<const float4*>(&Wl[c*68 + o0]);
            const float4 wb = *reinterpret_cast<const float4*>(&Wl[c*68 + o0 + 4]);
            const float4 xv = *reinterpret_cast<const float4*>(&Xl[c*132 + p0]);
            const float wr[8] = {wa.x,wa.y,wa.z,wa.w, wb.x,wb.y,wb.z,wb.w};
            const float xr[4] = {xv.x,xv.y,xv.z,xv.w};
#pragma unroll
            for (int k = 0; k < 8; ++k)
#pragma unroll
                for (int m = 0; m < 4; ++m) acc[k][m] += wr[k]*xr[m];
        }
        __syncthreads();
    }
#pragma unroll
    for (int k = 0; k < 8; ++k) {
        float4 o4;
        o4.x = gelu_f(acc[k][0]); o4.y = gelu_f(acc[k][1]);
        o4.z = gelu_f(acc[k][2]); o4.w = gelu_f(acc[k][3]);
        *reinterpret_cast<float4*>(&out[base + (size_t)(o0+k)*NPIX + p0]) = o4;
    }
}

// ---------------------------------------------------------------------------
// Depthwise 3x3 (pad 1) + bias + GELU.  grid = (H, B*C), block = 192 (=W).
// ---------------------------------------------------------------------------
__global__ __launch_bounds__(192) void k_dw(
    const float* __restrict__ t0, const float* __restrict__ w,
    const float* __restrict__ bias, float* __restrict__ g)
{
    const int x = threadIdx.x;
    const int y = blockIdx.x;
    const int bc = blockIdx.y;
    const int c = bc & 63;
    const float* img = t0 + bc * NPIX;
    const float* wc = w + c * 9;
    float acc = bias[c];
#pragma unroll
    for (int dy = -1; dy <= 1; ++dy) {
        const int yy = y + dy;
        if (yy < 0 || yy > 191) continue;
#pragma unroll
        for (int dx = -1; dx <= 1; ++dx) {
            const int xx = x + dx;
            if (xx < 0 || xx > 191) continue;
            acc += img[yy*WW + xx] * wc[(dy+1)*3 + (dx+1)];
        }
    }
    g[bc*NPIX + y*WW + x] = gelu_f(acc);
}

// ---------------------------------------------------------------------------
// Per-batch Gram G1 = X1 * X1^T: partial per 256-pixel chunk.
// ---------------------------------------------------------------------------
__global__ __launch_bounds__(256) void k_gram_part(
    const float* __restrict__ x1p, float* __restrict__ part)
{
    extern __shared__ float lt[];     // [256][68]
    const int chunk = blockIdx.x, b = blockIdx.y, t = threadIdx.x;
    const int gbase = b * (C*NPIX) + chunk * 256;
    for (int idx = t; idx < C*256; idx += 256) {
        const int c = idx >> 8, n = idx & 255;
        lt[n*68 + c] = x1p[gbase + c*NPIX + n];
    }
    __syncthreads();
    const int ti = t & 15, tj = t >> 4;
    float acc[4][4];
#pragma unroll
    for (int r = 0; r < 4; ++r)
#pragma unroll
        for (int s = 0; s < 4; ++s) acc[r][s] = 0.f;
    for (int n = 0; n < 256; ++n) {
        const float4 av = *reinterpret_cast<const float4*>(&lt[n*68 + 4*ti]);
        const float4 bv = *reinterpret_cast<const float4*>(&lt[n*68 + 4*tj]);
        const float ar[4] = {av.x, av.y, av.z, av.w};
        const float br[4] = {bv.x, bv.y, bv.z, bv.w};
#pragma unroll
        for (int r = 0; r < 4; ++r)
#pragma unroll
            for (int s = 0; s < 4; ++s) acc[r][s] += ar[r] * br[s];
    }
    float* pb = part + (b*144 + chunk)*4096;
#pragma unroll
    for (int r = 0; r < 4; ++r)
#pragma unroll
        for (int s = 0; s < 4; ++s) pb[(4*ti+r)*64 + (4*tj+s)] = acc[r][s];
}

__global__ __launch_bounds__(256) void k_gram_reduce(
    const float* __restrict__ part, float* __restrict__ G1)
{
    const int flat = blockIdx.x*256 + threadIdx.x;   // < 16384
    const int b = flat >> 12, ij = flat & 4095;
    float s = 0.f;
    for (int ch = 0; ch < 144; ++ch) s += part[(b*144+ch)*4096 + ij];
    G1[flat] = s;
}

// ---------------------------------------------------------------------------
// Channel-attention collapse: per batch, M2 = Wp * blockdiag(attn) * Wv.
// ---------------------------------------------------------------------------
__global__ __launch_bounds__(256) void k_attn_small(
    const float* __restrict__ G1a, const float* __restrict__ Wq,
    const float* __restrict__ Wk, const float* __restrict__ Wv,
    const float* __restrict__ Wp, const float* __restrict__ temp,
    float* __restrict__ M2)
{
    extern __shared__ float sm[];
    float* g1 = sm;
    float* wa = sm + 4096;
    float* wb = sm + 8192;
    float* u  = sm + 12288;
    float* at = sm + 16384;
    float* nq = sm + 18432;
    float* nk = sm + 18496;
    const int b = blockIdx.x, t = threadIdx.x;
    const float* G = G1a + b*4096;
    for (int i = t; i < 4096; i += 256) { g1[i] = G[i]; wa[i] = Wq[i]; wb[i] = Wk[i]; }
    __syncthreads();
    {
        const int r = t >> 2, q4 = t & 3;
        for (int cc = q4*16; cc < q4*16 + 16; ++cc) {
            float s = 0.f;
            for (int k = 0; k < 64; ++k) s += wa[r*64+k] * g1[k*64+cc];
            u[r*64+cc] = s;
        }
    }
    __syncthreads();
    {
        const int d = t >> 2, kq = t & 3;
        float p = 0.f;
        for (int k = kq*16; k < kq*16 + 16; ++k) {
            float tk = 0.f;
            for (int c2 = 0; c2 < 64; ++c2) tk += g1[k*64+c2] * wb[d*64+c2];
            p += wb[d*64+k] * tk;
        }
        p += __shfl_xor(p, 1);
        p += __shfl_xor(p, 2);
        if (kq == 0) nk[d] = sqrtf(fmaxf(p, 0.f));
    }
    if (t < 64) {
        float s = 0.f;
        for (int c2 = 0; c2 < 64; ++c2) s += u[t*64+c2] * wa[t*64+c2];
        nq[t] = sqrtf(fmaxf(s, 0.f));
    }
    __syncthreads();
    if (t < 64) {
        const int gI = t >> 5;
        const float tg = temp[gI];
        const float dq = fmaxf(nq[t], 1e-12f);
        float row[32];
        float mx = -1e30f;
#pragma unroll
        for (int d2 = 0; d2 < 32; ++d2) {
            const int dd = gI*32 + d2;
            float s = 0.f;
            for (int c2 = 0; c2 < 64; ++c2) s += u[t*64+c2] * wb[dd*64+c2];
            s = s * tg / (dq * fmaxf(nk[dd], 1e-12f));
            row[d2] = s; mx = fmaxf(mx, s);
        }
        float se = 0.f;
#pragma unroll
        for (int d2 = 0; d2 < 32; ++d2) { row[d2] = __expf(row[d2]-mx); se += row[d2]; }
        const float inv = 1.f / se;
#pragma unroll
        for (int d2 = 0; d2 < 32; ++d2) at[t*32+d2] = row[d2]*inv;
    }
    __syncthreads();
    for (int i = t; i < 4096; i += 256) { wa[i] = Wv[i]; wb[i] = Wp[i]; }
    __syncthreads();
    {
        const int m = t >> 2, q4 = t & 3, gI = m >> 5;
        for (int e = q4*16; e < q4*16 + 16; ++e) {
            float s = 0.f;
#pragma unroll
            for (int d2 = 0; d2 < 32; ++d2) s += at[m*32+d2] * wa[(gI*32+d2)*64 + e];
            g1[m*64+e] = s;
        }
    }
    __syncthreads();
    {
        const int o = t >> 2, q4 = t & 3;
        for (int e = q4*16; e < q4*16 + 16; ++e) {
            float s = 0.f;
            for (int m = 0; m < 64; ++m) s += wb[o*64+m] * g1[m*64+e];
            M2[b*4096 + o*64+e] = s;
        }
    }
}

// ---------------------------------------------------------------------------
// Small weight-folding products:
//  0: Wtr = rq^T rk   1: Wtc = cq^T ck
//  2: Wf2p = gr * Wf[:,64:128] @ rv   3: Wf3p = gc * Wf[:,128:192] @ cv
//  4: Wfx  = Wf[:,64:128] + Wf[:,128:192]
// ---------------------------------------------------------------------------
__global__ __launch_bounds__(256) void k_small_mats(
    const float* __restrict__ rq, const float* __restrict__ rk,
    const float* __restrict__ cq, const float* __restrict__ ck,
    const float* __restrict__ fw, const float* __restrict__ rv,
    const float* __restrict__ cv, const float* __restrict__ rg,
    const float* __restrict__ cg,
    float* __restrict__ Wtr, float* __restrict__ Wtc,
    float* __restrict__ Wf2p, float* __restrict__ Wf3p,
    float* __restrict__ Wfx)
{
    const int which = blockIdx.x, t = threadIdx.x;
    const int a = t >> 2, b0 = (t & 3) * 16;
    if (which <= 1) {
        const float* Q = which ? cq : rq;
        const float* Kw = which ? ck : rk;
        float* O = which ? Wtc : Wtr;
        for (int b = b0; b < b0 + 16; ++b) {
            float s = 0.f;
            for (int co = 0; co < 64; ++co) s += Q[co*64 + a] * Kw[co*64 + b];
            O[a*64 + b] = s;
        }
    } else if (which <= 3) {
        const float* Vw = (which == 2) ? rv : cv;
        const float g = (which == 2) ? rg[0] : cg[0];
        const int off = (which == 2) ? 64 : 128;
        float* O = (which == 2) ? Wf2p : Wf3p;
        for (int b = b0; b < b0 + 16; ++b) {
            float s = 0.f;
            for (int m = 0; m < 64; ++m) s += fw[a*192 + off + m] * Vw[m*64 + b];
            O[a*64 + b] = g * s;
        }
    } else {
        for (int b = b0; b < b0 + 16; ++b)
            Wfx[a*64 + b] = fw[a*192 + 64 + b] + fw[a*192 + 128 + b];
    }
}

// ---------------------------------------------------------------------------
// FUSED per-line attention, 2 blocks/CU via fp16 LDS intermediates.
// (R6 verified: occ 11->18%, VALUBusy 50->65%, 176->150 us.)
// ---------------------------------------------------------------------------
#define SP 196
__global__ __launch_bounds__(256, 2) void k_attn_fused(
    const float* __restrict__ X, const float* __restrict__ Wt,
    const float* __restrict__ U, float* __restrict__ Z)
{
    extern __shared__ float sm[];
    float* Xl = sm;                                   // [64][196] fp32
    __half* Ylh = reinterpret_cast<__half*>(sm + 12544);  // [64][196] fp16
    __half* Plh = reinterpret_cast<__half*>(sm);      // [192][196] fp16 overlay
    float* red  = sm;                                 // [192][17] overlay (ph3)
    float* mrow = sm + 3264;                          // 192 (in dead Xl)
    float* lrow = sm + 18816;                         // 192, persistent @75264B
    const int t = threadIdx.x;
    const int h = blockIdx.x, b = blockIdx.y;
    const size_t gbase = (size_t)b*(C*NPIX) + (size_t)h*WW;

    // --- phase 0: load X line ---
#pragma unroll 4
    for (int k = 0; k < 48; ++k) {
        const int idx = k*256 + t;
        const int c = idx / 192, j = idx - c*192;
        Xl[c*SP + j] = X[gbase + (size_t)c*NPIX + j];
    }
    __syncthreads();

    // --- phase 1: Y = Wt @ X (fp32 math), store fp16. Wt from global. ---
    {
        const int tc = t & 15, tjy = t >> 4;
        const int c0 = 4*tc, j0y = 12*tjy;
        float accy[4][12];
#pragma unroll
        for (int k = 0; k < 4; ++k)
#pragma unroll
            for (int m = 0; m < 12; ++m) accy[k][m] = 0.f;
        for (int a = 0; a < 64; ++a) {
            const float4 w4 = *reinterpret_cast<const float4*>(&Wt[a*64 + c0]);
            const float4 xa = *reinterpret_cast<const float4*>(&Xl[a*SP + j0y]);
            const float4 xb = *reinterpret_cast<const float4*>(&Xl[a*SP + j0y + 4]);
            const float4 xc = *reinterpret_cast<const float4*>(&Xl[a*SP + j0y + 8]);
            const float wr[4]  = {w4.x, w4.y, w4.z, w4.w};
            const float xr[12] = {xa.x,xa.y,xa.z,xa.w, xb.x,xb.y,xb.z,xb.w,
                                  xc.x,xc.y,xc.z,xc.w};
#pragma unroll
            for (int k = 0; k < 4; ++k)
#pragma unroll
                for (int m = 0; m < 12; ++m) accy[k][m] += wr[k] * xr[m];
        }
#pragma unroll
        for (int k = 0; k < 4; ++k) {
            __half2* yr = reinterpret_cast<__half2*>(&Ylh[(c0+k)*SP + j0y]);
#pragma unroll
            for (int q = 0; q < 6; ++q)
                yr[q] = __floats2half2_rn(accy[k][2*q], accy[k][2*q+1]);
        }
    }
    __syncthreads();

    // --- phase 2: S = X^T Y, fp32 12x12 per thread (Y converted on read) ---
    const int ti = t & 15, tj = t >> 4;
    const int i0 = ti*12, j0 = tj*12;
    float acc[12][12];
#pragma unroll
    for (int r = 0; r < 12; ++r)
#pragma unroll
        for (int s = 0; s < 12; ++s) acc[r][s] = 0.f;
#pragma unroll 2
    for (int c = 0; c < 64; ++c) {
        const float4 xa = *reinterpret_cast<const float4*>(&Xl[c*SP + i0]);
        const float4 xb = *reinterpret_cast<const float4*>(&Xl[c*SP + i0 + 4]);
        const float4 xc = *reinterpret_cast<const float4*>(&Xl[c*SP + i0 + 8]);
        const __half2* yp = reinterpret_cast<const __half2*>(&Ylh[c*SP + j0]);
        const float2 y0 = __half22float2(yp[0]);
        const float2 y1 = __half22float2(yp[1]);
        const float2 y2 = __half22float2(yp[2]);
        const float2 y3 = __half22float2(yp[3]);
        const float2 y4 = __half22float2(yp[4]);
        const float2 y5 = __half22float2(yp[5]);
        const float xr[12] = {xa.x,xa.y,xa.z,xa.w, xb.x,xb.y,xb.z,xb.w, xc.x,xc.y,xc.z,xc.w};
        const float yr[12] = {y0.x,y0.y, y1.x,y1.y, y2.x,y2.y,
                              y3.x,y3.y, y4.x,y4.y, y5.x,y5.y};
#pragma unroll
        for (int r = 0; r < 12; ++r)
#pragma unroll
            for (int s = 0; s < 12; ++s) acc[r][s] += xr[r] * yr[s];
    }
    __syncthreads();   // Xl/Ylh dead; red overlays Xl

    // --- phase 3: softmax over rows (fp32; P~ left unnormalized) ---
#pragma unroll
    for (int r = 0; r < 12; ++r) {
        float pm = acc[r][0];
#pragma unroll
        for (int s = 1; s < 12; ++s) pm = fmaxf(pm, acc[r][s]);
        red[(i0 + r)*17 + tj] = pm;
    }
    __syncthreads();
    if (t < 192) {
        float m = red[t*17];
#pragma unroll
        for (int k = 1; k < 16; ++k) m = fmaxf(m, red[t*17 + k]);
        mrow[t] = m;
    }
    __syncthreads();
#pragma unroll
    for (int r = 0; r < 12; ++r) {
        const float mi = mrow[i0 + r];
        float ps = 0.f;
#pragma unroll
        for (int s = 0; s < 12; ++s) {
            acc[r][s] = __expf(acc[r][s] - mi);
            ps += acc[r][s];
        }
        red[(i0 + r)*17 + tj] = ps;
    }
    __syncthreads();
    if (t < 192) {
        float l = 0.f;
#pragma unroll
        for (int k = 0; k < 16; ++k) l += red[t*17 + k];
        lrow[t] = 1.f / l;
    }
    __syncthreads();

    // --- phase 4: store unnormalized P~ as fp16 (overwrites red/Xl region) ---
#pragma unroll
    for (int r = 0; r < 12; ++r) {
        __half2* pr = reinterpret_cast<__half2*>(&Plh[(i0 + r)*SP + j0]);
#pragma unroll
        for (int q = 0; q < 6; ++q)
            pr[q] = __floats2half2_rn(acc[r][2*q], acc[r][2*q+1]);
    }
    __syncthreads();

    // --- phase 5: Z[c][i] = lrow[i] * sum_j U[c][j] P~[i][j];
    //     U streamed from global (L2-hot broadcast), P~ fp16 from LDS. ---
    const int ci = t & 15, ii = t >> 4;
    const int c0z = 4*ci, i0z = 12*ii;
    const float* Ub = U + gbase;
    float accz[4][12];
#pragma unroll
    for (int k = 0; k < 4; ++k)
#pragma unroll
        for (int m = 0; m < 12; ++m) accz[k][m] = 0.f;
#pragma unroll 2
    for (int jq = 0; jq < 48; ++jq) {
        const int j4 = 4*jq;
        float4 u4[4];
#pragma unroll
        for (int k = 0; k < 4; ++k)
            u4[k] = *reinterpret_cast<const float4*>(&Ub[(size_t)(c0z+k)*NPIX + j4]);
        float2 pa[12], pb[12];
#pragma unroll
        for (int m = 0; m < 12; ++m) {
            const __half2* pp = reinterpret_cast<const __half2*>(&Plh[(i0z+m)*SP + j4]);
            pa[m] = __half22float2(pp[0]);
            pb[m] = __half22float2(pp[1]);
        }
#pragma unroll
        for (int k = 0; k < 4; ++k)
#pragma unroll
            for (int m = 0; m < 12; ++m) {
                accz[k][m] += u4[k].x * pa[m].x + u4[k].y * pa[m].y
                            + u4[k].z * pb[m].x + u4[k].w * pb[m].y;
            }
    }
    float lr[12];
#pragma unroll
    for (int m = 0; m < 12; ++m) lr[m] = lrow[i0z + m];
#pragma unroll
    for (int k = 0; k < 4; ++k) {
        float* zr = Z + gbase + (size_t)(c0z + k)*NPIX + i0z;
        float4 o0, o1, o2;
        o0.x = accz[k][0]*lr[0]; o0.y = accz[k][1]*lr[1];  o0.z = accz[k][2]*lr[2];   o0.w = accz[k][3]*lr[3];
        o1.x = accz[k][4]*lr[4]; o1.y = accz[k][5]*lr[5];  o1.z = accz[k][6]*lr[6];   o1.w = accz[k][7]*lr[7];
        o2.x = accz[k][8]*lr[8]; o2.y = accz[k][9]*lr[9];  o2.z = accz[k][10]*lr[10]; o2.w = accz[k][11]*lr[11];
        *reinterpret_cast<float4*>(zr)     = o0;
        *reinterpret_cast<float4*>(zr + 4) = o1;
        *reinterpret_cast<float4*>(zr + 8) = o2;
    }
}

// ---------------------------------------------------------------------------
// HW transpose per image: out[img][x][y] = in[img][y][x]. grid (6,6,B*C).
// ---------------------------------------------------------------------------
__global__ __launch_bounds__(256) void k_transpose(
    const float* __restrict__ in, float* __restrict__ out)
{
    __shared__ float tile[32][33];
    const int tx = threadIdx.x & 31, ty = threadIdx.x >> 5;
    const int x0 = blockIdx.x*32, y0 = blockIdx.y*32;
    const float* img = in + blockIdx.z * NPIX;
    float* og = out + blockIdx.z * NPIX;
#pragma unroll
    for (int r = ty; r < 32; r += 8) tile[r][tx] = img[(y0+r)*WW + x0+tx];
    __syncthreads();
#pragma unroll
    for (int r = ty; r < 32; r += 8) og[(x0+r)*WW + (y0+tx)] = tile[tx][r];
}

// ---------------------------------------------------------------------------
// Dual transpose: z < B*C -> inA->outA, else inB->outB (one launch ramp).
// ---------------------------------------------------------------------------
__global__ __launch_bounds__(256) void k_transpose2(
    const float* __restrict__ inA, float* __restrict__ outA,
    const float* __restrict__ inB, float* __restrict__ outB)
{
    __shared__ float tile[32][33];
    const int tx = threadIdx.x & 31, ty = threadIdx.x >> 5;
    const int x0 = blockIdx.x*32, y0 = blockIdx.y*32;
    const int z = blockIdx.z;
    const float* img = (z < BB*C) ? inA + (size_t)z*NPIX
                                  : inB + (size_t)(z - BB*C)*NPIX;
    float* og = (z < BB*C) ? outA + (size_t)z*NPIX
                           : outB + (size_t)(z - BB*C)*NPIX;
#pragma unroll
    for (int r = ty; r < 32; r += 8) tile[r][tx] = img[(y0+r)*WW + x0+tx];
    __syncthreads();
#pragma unroll
    for (int r = ty; r < 32; r += 8) og[(x0+r)*WW + (y0+tx)] = tile[tx][r];
}

// ---------------------------------------------------------------------------
extern "C" void kernel_launch(void* const* d_in, const int* in_sizes, int n_in,
                              void* d_out, int out_size, void* d_ws, size_t ws_size,
                              hipStream_t stream) {
    const float* x       = (const float*)d_in[0];
    const float* pw_w    = (const float*)d_in[1];
    const float* dw_w    = (const float*)d_in[2];
    const float* dw_b    = (const float*)d_in[3];
    const float* conv2_w = (const float*)d_in[4];
    const float* conv2_b = (const float*)d_in[5];
    const float* conv0_w = (const float*)d_in[6];
    const float* conv0_b = (const float*)d_in[7];
    const float* attq    = (const float*)d_in[8];
    const float* attk    = (const float*)d_in[9];
    const float* attv    = (const float*)d_in[10];
    const float* attp    = (const float*)d_in[11];
    const float* temp    = (const float*)d_in[12];
    const float* rq      = (const float*)d_in[13];
    const float* rk      = (const float*)d_in[14];
    const float* rv      = (const float*)d_in[15];
    const float* rg      = (const float*)d_in[16];
    const float* cq      = (const float*)d_in[17];
    const float* ck      = (const float*)d_in[18];
    const float* cv      = (const float*)d_in[19];
    const float* cg      = (const float*)d_in[20];
    const float* fw      = (const float*)d_in[21];
    const float* fb      = (const float*)d_in[22];

    float* ws = (float*)d_ws;
    float* A  = ws;                 // t0 -> x1 (lives to end)
    float* Bf = ws + (size_t)ST;    // g -> out1
    float* Cf = ws + 2*(size_t)ST;  // x1t -> Z2
    float* Df = ws + 3*(size_t)ST;  // out1t -> Z3
    float* Ef = ws + 4*(size_t)ST;  // Z3t
    float* partials = ws + 5*(size_t)ST;   // 576*4096 = 2359296 floats
    float* G1 = partials + 576*4096;       // 16384
    float* M2 = G1 + 16384;                // 16384
    float* Wtr  = M2 + 16384;              // 5 x 4096
    float* Wtc  = Wtr + 4096;
    float* Wf2p = Wtc + 4096;
    float* Wf3p = Wf2p + 4096;
    float* Wfx  = Wf3p + 4096;

    const size_t need = ((size_t)5*ST + 576*4096 + 16384 + 16384 + 5*4096)
                        * sizeof(float);
    if (ws_size < need) {
        fprintf(stderr, "kernel_launch: ws_size %zu < needed %zu\n", ws_size, need);
        return;
    }

    (void)hipFuncSetAttribute((const void*)k_gram_part,
        hipFuncAttributeMaxDynamicSharedMemorySize, 69632);
    (void)hipFuncSetAttribute((const void*)k_attn_small,
        hipFuncAttributeMaxDynamicSharedMemorySize, 74240);
    (void)hipFuncSetAttribute((const void*)k_attn_fused,
        hipFuncAttributeMaxDynamicSharedMemorySize, 76032);
    (void)hipFuncSetAttribute((const void*)k_conv4,
        hipFuncAttributeMaxDynamicSharedMemorySize, 51200);
    (void)hipFuncSetAttribute((const void*)(k_gconv<false,false,false>),
        hipFuncAttributeMaxDynamicSharedMemorySize, 51200);
    (void)hipFuncSetAttribute((const void*)(k_gconv<true,false,false>),
        hipFuncAttributeMaxDynamicSharedMemorySize, 51200);
    (void)hipFuncSetAttribute((const void*)(k_gconv<false,true,false>),
        hipFuncAttributeMaxDynamicSharedMemorySize, 51200);

    const dim3 blk256(256), blk192(192);
    const dim3 gconv(NPIX/128, BB);      // (288, 4)
    const dim3 ggram(NPIX/256, BB);      // (144, 4)
    const dim3 gline(HH, BB);            // (192, 4)
    const dim3 gtr(6, 6, BB*C);
    const dim3 gtr2(6, 6, 2*BB*C);

    // 0) fold weights
    k_small_mats<<<dim3(5), blk256, 0, stream>>>(rq, rk, cq, ck, fw, rv, cv,
                                                 rg, cg, Wtr, Wtc, Wf2p, Wf3p, Wfx);
    // 1) A = pw_w @ x
    k_gconv<false,false,false><<<gconv, blk256, 51200, stream>>>(
        x, nullptr, pw_w, nullptr, nullptr, nullptr, A, 64, 64);
    // 2) B = gelu(dw3x3(A) + dw_b)
    k_dw<<<dim3(HH, BB*C), blk192, 0, stream>>>(A, dw_w, dw_b, Bf);
    // 3) A = x1 = conv2@B + conv0@x + conv2_b + conv0_b
    k_gconv<true,false,false><<<gconv, blk256, 51200, stream>>>(
        Bf, x, conv2_w, conv0_w, conv2_b, conv0_b, A, 64, 64);
    // 4) channel attention collapse -> M2
    k_gram_part<<<ggram, blk256, 69632, stream>>>(A, partials);
    k_gram_reduce<<<dim3(64), blk256, 0, stream>>>(partials, G1);
    k_attn_small<<<dim3(BB), blk256, 74240, stream>>>(G1, attq, attk, attv, attp, temp, M2);
    // 5) B = out1 = M2[b] @ x1
    k_gconv<false,true,false><<<gconv, blk256, 51200, stream>>>(
        A, nullptr, M2, nullptr, nullptr, nullptr, Bf, 64, 64);
    // 6) C = x1t, D = out1t (one dual-transpose launch)
    k_transpose2<<<gtr2, blk256, 0, stream>>>(A, Cf, Bf, Df);
    // 7) col attention fused: E = Z3t
    k_attn_fused<<<gline, blk256, 76032, stream>>>(Cf, Wtc, Df, Ef);
    // 8) D = Z3 = transpose(Z3t)
    k_transpose<<<gtr, blk256, 0, stream>>>(Ef, Df);
    // 9) row attention fused: C = Z2
    k_attn_fused<<<gline, blk256, 76032, stream>>>(A, Wtr, Bf, Cf);
    // 10) FUSED final conv: out = gelu(fw[:,0:64]@out1 + Wf2p@Z2 + Wf3p@Z3
    //                                   + Wfx@x1 + fb)
    k_conv4<<<gconv, blk256, 51200, stream>>>(
        Bf, Cf, Df, A, fw, Wf2p, Wf3p, Wfx, fb, (float*)d_out);
}

// Round 11
// 810.330 us; speedup vs baseline: 1.5351x; 1.0381x over previous
//
#include <hip/hip_runtime.h>
#include <cstdio>

#define BB 4
#define C 64
#define HH 192
#define WW 192
#define NPIX (HH*WW)            /* 36864 */
#define ST (BB*C*NPIX)          /* 9437184 floats per tensor */

__device__ __forceinline__ float gelu_f(float v) {
    return 0.5f * v * (1.0f + erff(v * 0.70710678118654752440f));
}

// ---- fp16 pair helpers (dot2 path). h2 uses __fp16 to match the native
// return type of __builtin_amdgcn_cvt_pkrtz on gfx950 (R10 compile fix). ----
typedef __fp16 h2 __attribute__((ext_vector_type(2)));

__device__ __forceinline__ h2 pkh2(float lo, float hi) {
#if __has_builtin(__builtin_amdgcn_cvt_pkrtz)
    return __builtin_amdgcn_cvt_pkrtz(lo, hi);
#else
    h2 r; r[0] = (__fp16)lo; r[1] = (__fp16)hi; return r;
#endif
}

__device__ __forceinline__ float dot2f(h2 a, h2 b, float c) {
#if __has_builtin(__builtin_amdgcn_fdot2)
    return __builtin_amdgcn_fdot2(a, b, c, false);
#else
    return c + (float)a[0]*(float)b[0] + (float)a[1]*(float)b[1];
#endif
}

__device__ __forceinline__ void ld4h2(const void* p, h2* d) {
    const float4 f = *reinterpret_cast<const float4*>(p);
    d[0] = __builtin_bit_cast(h2, f.x);
    d[1] = __builtin_bit_cast(h2, f.y);
    d[2] = __builtin_bit_cast(h2, f.z);
    d[3] = __builtin_bit_cast(h2, f.w);
}

// ---------------------------------------------------------------------------
// GEMM-style 1x1 conv (R8-validated). 64(o) x 128(px) tile, 256 thr,
// acc[8][4]/thread. LDS 51200 B -> 3 blocks/CU.
// ---------------------------------------------------------------------------
template<bool TWO_IN, bool PERB, bool DO_GELU>
__global__ __launch_bounds__(256, 3) void k_gconv(
    const float* __restrict__ in1, const float* __restrict__ in2,
    const float* __restrict__ W1, const float* __restrict__ W2,
    const float* __restrict__ bias1, const float* __restrict__ bias2,
    float* __restrict__ out, int ldw1, int ldw2)
{
    extern __shared__ float sm[];
    float* Wl = sm;            // [64][68]  Wl[c][o] = W[o][c]
    float* Xl = sm + 4352;     // [64][132] Xl[c][p]
    const int t = threadIdx.x;
    const int px0 = blockIdx.x * 128;
    const int b = blockIdx.y;
    const size_t base = (size_t)b*(C*NPIX) + px0;
    const int to = t >> 5, tp = t & 31;
    const int o0 = to*8, p0 = tp*4;
    float acc[8][4];
#pragma unroll
    for (int k = 0; k < 8; ++k) {
        float bo = 0.f;
        if (bias1) bo += bias1[o0+k];
        if (bias2) bo += bias2[o0+k];
#pragma unroll
        for (int m = 0; m < 4; ++m) acc[k][m] = bo;
    }
    const int NIN = TWO_IN ? 2 : 1;
#pragma unroll
    for (int inp = 0; inp < NIN; ++inp) {
        const float* In = inp ? in2 : in1;
        const float* Wk = inp ? W2 : (PERB ? W1 + b*4096 : W1);
        const int ldw = inp ? ldw2 : ldw1;
#pragma unroll
        for (int k = 0; k < 16; ++k) {
            const int idx = k*256 + t;
            const int o = idx >> 6, c = idx & 63;
            Wl[c*68 + o] = Wk[o*ldw + c];
        }
#pragma unroll
        for (int k = 0; k < 8; ++k) {
            const int f4 = k*256 + t;
            const int c = f4 >> 5, p4 = (f4 & 31)*4;
            *reinterpret_cast<float4*>(&Xl[c*132 + p4]) =
                *reinterpret_cast<const float4*>(&In[base + (size_t)c*NPIX + p4]);
        }
        __syncthreads();
#pragma unroll 2
        for (int c = 0; c < 64; ++c) {
            const float4 wa = *reinterpret_cast<const float4*>(&Wl[c*68 + o0]);
            const float4 wb = *reinterpret_cast<const float4*>(&Wl[c*68 + o0 + 4]);
            const float4 xv = *reinterpret_cast<const float4*>(&Xl[c*132 + p0]);
            const float wr[8] = {wa.x,wa.y,wa.z,wa.w, wb.x,wb.y,wb.z,wb.w};
            const float xr[4] = {xv.x,xv.y,xv.z,xv.w};
#pragma unroll
            for (int k = 0; k < 8; ++k)
#pragma unroll
                for (int m = 0; m < 4; ++m) acc[k][m] += wr[k]*xr[m];
        }
        __syncthreads();
    }
#pragma unroll
    for (int k = 0; k < 8; ++k) {
        float4 o4;
        if (DO_GELU) {
            o4.x = gelu_f(acc[k][0]); o4.y = gelu_f(acc[k][1]);
            o4.z = gelu_f(acc[k][2]); o4.w = gelu_f(acc[k][3]);
        } else {
            o4.x = acc[k][0]; o4.y = acc[k][1];
            o4.z = acc[k][2]; o4.w = acc[k][3];
        }
        *reinterpret_cast<float4*>(&out[base + (size_t)(o0+k)*NPIX + p0]) = o4;
    }
}

// ---------------------------------------------------------------------------
// FUSED final conv: out = gelu(W1@i1 + W2@i2 + W3@i3 + W4@i4 + bias).
// Same tile geometry as k_gconv; validated R7.
// ---------------------------------------------------------------------------
__global__ __launch_bounds__(256, 3) void k_conv4(
    const float* __restrict__ i1, const float* __restrict__ i2,
    const float* __restrict__ i3, const float* __restrict__ i4,
    const float* __restrict__ W1, const float* __restrict__ W2,
    const float* __restrict__ W3, const float* __restrict__ W4,
    const float* __restrict__ bias, float* __restrict__ out)
{
    extern __shared__ float sm[];
    float* Wl = sm;            // [64][68]
    float* Xl = sm + 4352;     // [64][132]
    const int t = threadIdx.x;
    const int px0 = blockIdx.x * 128;
    const int b = blockIdx.y;
    const size_t base = (size_t)b*(C*NPIX) + px0;
    const int to = t >> 5, tp = t & 31;
    const int o0 = to*8, p0 = tp*4;
    float acc[8][4];
#pragma unroll
    for (int k = 0; k < 8; ++k) {
        const float bo = bias[o0+k];
#pragma unroll
        for (int m = 0; m < 4; ++m) acc[k][m] = bo;
    }
#pragma unroll
    for (int inp = 0; inp < 4; ++inp) {
        const float* In = (inp==0)?i1:(inp==1)?i2:(inp==2)?i3:i4;
        const float* Wk = (inp==0)?W1:(inp==1)?W2:(inp==2)?W3:W4;
        const int ldw = (inp==0)?192:64;
#pragma unroll
        for (int k = 0; k < 16; ++k) {
            const int idx = k*256 + t;
            const int o = idx >> 6, c = idx & 63;
            Wl[c*68 + o] = Wk[o*ldw + c];
        }
#pragma unroll
        for (int k = 0; k < 8; ++k) {
            const int f4 = k*256 + t;
            const int c = f4 >> 5, p4 = (f4 & 31)*4;
            *reinterpret_cast<float4*>(&Xl[c*132 + p4]) =
                *reinterpret_cast<const float4*>(&In[base + (size_t)c*NPIX + p4]);
        }
        __syncthreads();
#pragma unroll 2
        for (int c = 0; c < 64; ++c) {
            const float4 wa = *reinterpret_cast<const float4*>(&Wl[c*68 + o0]);
            const float4 wb = *reinterpret_cast<const float4*>(&Wl[c*68 + o0 + 4]);
            const float4 xv = *reinterpret_cast<const float4*>(&Xl[c*132 + p0]);
            const float wr[8] = {wa.x,wa.y,wa.z,wa.w, wb.x,wb.y,wb.z,wb.w};
            const float xr[4] = {xv.x,xv.y,xv.z,xv.w};
#pragma unroll
            for (int k = 0; k < 8; ++k)
#pragma unroll
                for (int m = 0; m < 4; ++m) acc[k][m] += wr[k]*xr[m];
        }
        __syncthreads();
    }
#pragma unroll
    for (int k = 0; k < 8; ++k) {
        float4 o4;
        o4.x = gelu_f(acc[k][0]); o4.y = gelu_f(acc[k][1]);
        o4.z = gelu_f(acc[k][2]); o4.w = gelu_f(acc[k][3]);
        *reinterpret_cast<float4*>(&out[base + (size_t)(o0+k)*NPIX + p0]) = o4;
    }
}

// ---------------------------------------------------------------------------
// Depthwise 3x3 (pad 1) + bias + GELU.  grid = (H, B*C), block = 192 (=W).
// ---------------------------------------------------------------------------
__global__ __launch_bounds__(192) void k_dw(
    const float* __restrict__ t0, const float* __restrict__ w,
    const float* __restrict__ bias, float* __restrict__ g)
{
    const int x = threadIdx.x;
    const int y = blockIdx.x;
    const int bc = blockIdx.y;
    const int c = bc & 63;
    const float* img = t0 + bc * NPIX;
    const float* wc = w + c * 9;
    float acc = bias[c];
#pragma unroll
    for (int dy = -1; dy <= 1; ++dy) {
        const int yy = y + dy;
        if (yy < 0 || yy > 191) continue;
#pragma unroll
        for (int dx = -1; dx <= 1; ++dx) {
            const int xx = x + dx;
            if (xx < 0 || xx > 191) continue;
            acc += img[yy*WW + xx] * wc[(dy+1)*3 + (dx+1)];
        }
    }
    g[bc*NPIX + y*WW + x] = gelu_f(acc);
}

// ---------------------------------------------------------------------------
// Per-batch Gram G1 = X1 * X1^T: partial per 256-pixel chunk.
// ---------------------------------------------------------------------------
__global__ __launch_bounds__(256) void k_gram_part(
    const float* __restrict__ x1p, float* __restrict__ part)
{
    extern __shared__ float lt[];     // [256][68]
    const int chunk = blockIdx.x, b = blockIdx.y, t = threadIdx.x;
    const int gbase = b * (C*NPIX) + chunk * 256;
    for (int idx = t; idx < C*256; idx += 256) {
        const int c = idx >> 8, n = idx & 255;
        lt[n*68 + c] = x1p[gbase + c*NPIX + n];
    }
    __syncthreads();
    const int ti = t & 15, tj = t >> 4;
    float acc[4][4];
#pragma unroll
    for (int r = 0; r < 4; ++r)
#pragma unroll
        for (int s = 0; s < 4; ++s) acc[r][s] = 0.f;
    for (int n = 0; n < 256; ++n) {
        const float4 av = *reinterpret_cast<const float4*>(&lt[n*68 + 4*ti]);
        const float4 bv = *reinterpret_cast<const float4*>(&lt[n*68 + 4*tj]);
        const float ar[4] = {av.x, av.y, av.z, av.w};
        const float br[4] = {bv.x, bv.y, bv.z, bv.w};
#pragma unroll
        for (int r = 0; r < 4; ++r)
#pragma unroll
            for (int s = 0; s < 4; ++s) acc[r][s] += ar[r] * br[s];
    }
    float* pb = part + (b*144 + chunk)*4096;
#pragma unroll
    for (int r = 0; r < 4; ++r)
#pragma unroll
        for (int s = 0; s < 4; ++s) pb[(4*ti+r)*64 + (4*tj+s)] = acc[r][s];
}

__global__ __launch_bounds__(256) void k_gram_reduce(
    const float* __restrict__ part, float* __restrict__ G1)
{
    const int flat = blockIdx.x*256 + threadIdx.x;   // < 16384
    const int b = flat >> 12, ij = flat & 4095;
    float s = 0.f;
    for (int ch = 0; ch < 144; ++ch) s += part[(b*144+ch)*4096 + ij];
    G1[flat] = s;
}

// ---------------------------------------------------------------------------
// Channel-attention collapse: per batch, M2 = Wp * blockdiag(attn) * Wv.
// ---------------------------------------------------------------------------
__global__ __launch_bounds__(256) void k_attn_small(
    const float* __restrict__ G1a, const float* __restrict__ Wq,
    const float* __restrict__ Wk, const float* __restrict__ Wv,
    const float* __restrict__ Wp, const float* __restrict__ temp,
    float* __restrict__ M2)
{
    extern __shared__ float sm[];
    float* g1 = sm;
    float* wa = sm + 4096;
    float* wb = sm + 8192;
    float* u  = sm + 12288;
    float* at = sm + 16384;
    float* nq = sm + 18432;
    float* nk = sm + 18496;
    const int b = blockIdx.x, t = threadIdx.x;
    const float* G = G1a + b*4096;
    for (int i = t; i < 4096; i += 256) { g1[i] = G[i]; wa[i] = Wq[i]; wb[i] = Wk[i]; }
    __syncthreads();
    {
        const int r = t >> 2, q4 = t & 3;
        for (int cc = q4*16; cc < q4*16 + 16; ++cc) {
            float s = 0.f;
            for (int k = 0; k < 64; ++k) s += wa[r*64+k] * g1[k*64+cc];
            u[r*64+cc] = s;
        }
    }
    __syncthreads();
    {
        const int d = t >> 2, kq = t & 3;
        float p = 0.f;
        for (int k = kq*16; k < kq*16 + 16; ++k) {
            float tk = 0.f;
            for (int c2 = 0; c2 < 64; ++c2) tk += g1[k*64+c2] * wb[d*64+c2];
            p += wb[d*64+k] * tk;
        }
        p += __shfl_xor(p, 1);
        p += __shfl_xor(p, 2);
        if (kq == 0) nk[d] = sqrtf(fmaxf(p, 0.f));
    }
    if (t < 64) {
        float s = 0.f;
        for (int c2 = 0; c2 < 64; ++c2) s += u[t*64+c2] * wa[t*64+c2];
        nq[t] = sqrtf(fmaxf(s, 0.f));
    }
    __syncthreads();
    if (t < 64) {
        const int gI = t >> 5;
        const float tg = temp[gI];
        const float dq = fmaxf(nq[t], 1e-12f);
        float row[32];
        float mx = -1e30f;
#pragma unroll
        for (int d2 = 0; d2 < 32; ++d2) {
            const int dd = gI*32 + d2;
            float s = 0.f;
            for (int c2 = 0; c2 < 64; ++c2) s += u[t*64+c2] * wb[dd*64+c2];
            s = s * tg / (dq * fmaxf(nk[dd], 1e-12f));
            row[d2] = s; mx = fmaxf(mx, s);
        }
        float se = 0.f;
#pragma unroll
        for (int d2 = 0; d2 < 32; ++d2) { row[d2] = __expf(row[d2]-mx); se += row[d2]; }
        const float inv = 1.f / se;
#pragma unroll
        for (int d2 = 0; d2 < 32; ++d2) at[t*32+d2] = row[d2]*inv;
    }
    __syncthreads();
    for (int i = t; i < 4096; i += 256) { wa[i] = Wv[i]; wb[i] = Wp[i]; }
    __syncthreads();
    {
        const int m = t >> 2, q4 = t & 3, gI = m >> 5;
        for (int e = q4*16; e < q4*16 + 16; ++e) {
            float s = 0.f;
#pragma unroll
            for (int d2 = 0; d2 < 32; ++d2) s += at[m*32+d2] * wa[(gI*32+d2)*64 + e];
            g1[m*64+e] = s;
        }
    }
    __syncthreads();
    {
        const int o = t >> 2, q4 = t & 3;
        for (int e = q4*16; e < q4*16 + 16; ++e) {
            float s = 0.f;
            for (int m = 0; m < 64; ++m) s += wb[o*64+m] * g1[m*64+e];
            M2[b*4096 + o*64+e] = s;
        }
    }
}

// ---------------------------------------------------------------------------
// Small weight-folding products:
//  0: Wtr = rq^T rk   1: Wtc = cq^T ck
//  2: Wf2p = gr * Wf[:,64:128] @ rv   3: Wf3p = gc * Wf[:,128:192] @ cv
//  4: Wfx  = Wf[:,64:128] + Wf[:,128:192]
// ---------------------------------------------------------------------------
__global__ __launch_bounds__(256) void k_small_mats(
    const float* __restrict__ rq, const float* __restrict__ rk,
    const float* __restrict__ cq, const float* __restrict__ ck,
    const float* __restrict__ fw, const float* __restrict__ rv,
    const float* __restrict__ cv, const float* __restrict__ rg,
    const float* __restrict__ cg,
    float* __restrict__ Wtr, float* __restrict__ Wtc,
    float* __restrict__ Wf2p, float* __restrict__ Wf3p,
    float* __restrict__ Wfx)
{
    const int which = blockIdx.x, t = threadIdx.x;
    const int a = t >> 2, b0 = (t & 3) * 16;
    if (which <= 1) {
        const float* Q = which ? cq : rq;
        const float* Kw = which ? ck : rk;
        float* O = which ? Wtc : Wtr;
        for (int b = b0; b < b0 + 16; ++b) {
            float s = 0.f;
            for (int co = 0; co < 64; ++co) s += Q[co*64 + a] * Kw[co*64 + b];
            O[a*64 + b] = s;
        }
    } else if (which <= 3) {
        const float* Vw = (which == 2) ? rv : cv;
        const float g = (which == 2) ? rg[0] : cg[0];
        const int off = (which == 2) ? 64 : 128;
        float* O = (which == 2) ? Wf2p : Wf3p;
        for (int b = b0; b < b0 + 16; ++b) {
            float s = 0.f;
            for (int m = 0; m < 64; ++m) s += fw[a*192 + off + m] * Vw[m*64 + b];
            O[a*64 + b] = g * s;
        }
    } else {
        for (int b = b0; b < b0 + 16; ++b)
            Wfx[a*64 + b] = fw[a*192 + 64 + b] + fw[a*192 + 128 + b];
    }
}

// ---------------------------------------------------------------------------
// FUSED per-line attention, 2 blocks/CU, v_dot2_f32_f16 math.
//   All three GEMM phases use fp16-pair operands with fp32 accumulate:
//   ph1: Y[c][j]=sum_a Wt[a][c]X[a][j]   (X pairs along c; Wt cvt'd on fly)
//   ph2: S[i][j]=sum_c X[c][i]Y[c][j]    (X,Y pairs along c)
//   ph5: Z[c][i]=lrow[i]*sum_j U[c][j]P~[i][j] (P~ pairs along j; U cvt'd)
//   Softmax fp32 in registers (unchanged from R6).
// LDS (bytes): phase A: Xh h2[32][196]@0 (25088) + Yh h2[32][196]@25088
//              phase B: Ph h2[192][100]@0 (76800; stride 100 for b128 align)
//              red/mrow overlay dead Xh; lrow @76800 (768)
// dyn LDS = 77568 -> 2 blocks/CU (R6-verified occupancy structure).
// Instruction count ~halved vs R8 (dot2 = 2 MAC/inst).
// ---------------------------------------------------------------------------
#define SP 196
#define PSTR 100
__global__ __launch_bounds__(256, 2) void k_attn_fused(
    const float* __restrict__ X, const float* __restrict__ Wt,
    const float* __restrict__ U, float* __restrict__ Z)
{
    extern __shared__ float sm[];
    h2* Xh = reinterpret_cast<h2*>(sm);            // [32][196] pairs along c
    h2* Yh = reinterpret_cast<h2*>(sm + 6272);     // [32][196] pairs along c
    h2* Ph = reinterpret_cast<h2*>(sm);            // [192][100] pairs along j
    float* red  = sm;                              // [192][17] overlay (ph3)
    float* mrow = sm + 3264;                       // 192 (in dead Xh)
    float* lrow = sm + 19200;                      // 192, persistent @76800B
    const int t = threadIdx.x;
    const int h = blockIdx.x, b = blockIdx.y;
    const size_t gbase = (size_t)b*(C*NPIX) + (size_t)h*WW;

    // --- phase 0: load X line, pack fp16 pairs along c ---
#pragma unroll 4
    for (int k = 0; k < 24; ++k) {
        const int idx = k*256 + t;                 // < 32*192
        const int cc = idx / 192, j = idx - cc*192;
        const float lo = X[gbase + (size_t)(2*cc)*NPIX + j];
        const float hi = X[gbase + (size_t)(2*cc+1)*NPIX + j];
        Xh[cc*SP + j] = pkh2(lo, hi);
    }
    __syncthreads();

    // --- phase 1: Y = sum_a Wt[a][c] X[a][j], dot2 pairs along a ---
    {
        const int tc = t & 15, tjy = t >> 4;
        const int c0 = 4*tc, j0y = 12*tjy;
        float accy[4][12];
#pragma unroll
        for (int k = 0; k < 4; ++k)
#pragma unroll
            for (int m = 0; m < 12; ++m) accy[k][m] = 0.f;
        for (int aa = 0; aa < 32; ++aa) {
            const float4 wlo = *reinterpret_cast<const float4*>(&Wt[(2*aa)*64 + c0]);
            const float4 whi = *reinterpret_cast<const float4*>(&Wt[(2*aa+1)*64 + c0]);
            h2 wh[4];
            wh[0] = pkh2(wlo.x, whi.x); wh[1] = pkh2(wlo.y, whi.y);
            wh[2] = pkh2(wlo.z, whi.z); wh[3] = pkh2(wlo.w, whi.w);
            h2 xh[12];
            ld4h2(&Xh[aa*SP + j0y],     xh);
            ld4h2(&Xh[aa*SP + j0y + 4], xh+4);
            ld4h2(&Xh[aa*SP + j0y + 8], xh+8);
#pragma unroll
            for (int k = 0; k < 4; ++k)
#pragma unroll
                for (int m = 0; m < 12; ++m)
                    accy[k][m] = dot2f(wh[k], xh[m], accy[k][m]);
        }
#pragma unroll
        for (int m = 0; m < 12; ++m) {
            Yh[(2*tc)*SP + j0y + m]   = pkh2(accy[0][m], accy[1][m]);
            Yh[(2*tc+1)*SP + j0y + m] = pkh2(accy[2][m], accy[3][m]);
        }
    }
    __syncthreads();

    // --- phase 2: S = X^T Y, dot2 pairs along c, fp32 12x12 acc ---
    const int ti = t & 15, tj = t >> 4;
    const int i0 = ti*12, j0 = tj*12;
    float acc[12][12];
#pragma unroll
    for (int r = 0; r < 12; ++r)
#pragma unroll
        for (int s = 0; s < 12; ++s) acc[r][s] = 0.f;
#pragma unroll 2
    for (int cc = 0; cc < 32; ++cc) {
        h2 xh[12], yh[12];
        ld4h2(&Xh[cc*SP + i0],     xh);
        ld4h2(&Xh[cc*SP + i0 + 4], xh+4);
        ld4h2(&Xh[cc*SP + i0 + 8], xh+8);
        ld4h2(&Yh[cc*SP + j0],     yh);
        ld4h2(&Yh[cc*SP + j0 + 4], yh+4);
        ld4h2(&Yh[cc*SP + j0 + 8], yh+8);
#pragma unroll
        for (int r = 0; r < 12; ++r)
#pragma unroll
            for (int s = 0; s < 12; ++s)
                acc[r][s] = dot2f(xh[r], yh[s], acc[r][s]);
    }
    __syncthreads();   // Xh/Yh dead; red overlays Xh

    // --- phase 3: softmax over rows (fp32; P~ left unnormalized) ---
#pragma unroll
    for (int r = 0; r < 12; ++r) {
        float pm = acc[r][0];
#pragma unroll
        for (int s = 1; s < 12; ++s) pm = fmaxf(pm, acc[r][s]);
        red[(i0 + r)*17 + tj] = pm;
    }
    __syncthreads();
    if (t < 192) {
        float m = red[t*17];
#pragma unroll
        for (int k = 1; k < 16; ++k) m = fmaxf(m, red[t*17 + k]);
        mrow[t] = m;
    }
    __syncthreads();
#pragma unroll
    for (int r = 0; r < 12; ++r) {
        const float mi = mrow[i0 + r];
        float ps = 0.f;
#pragma unroll
        for (int s = 0; s < 12; ++s) {
            acc[r][s] = __expf(acc[r][s] - mi);
            ps += acc[r][s];
        }
        red[(i0 + r)*17 + tj] = ps;
    }
    __syncthreads();
    if (t < 192) {
        float l = 0.f;
#pragma unroll
        for (int k = 0; k < 16; ++k) l += red[t*17 + k];
        lrow[t] = 1.f / l;
    }
    __syncthreads();

    // --- phase 4: store unnormalized P~ fp16, pairs along j ---
    {
        const int jh0 = j0 >> 1;       // 6*tj
#pragma unroll
        for (int r = 0; r < 12; ++r)
#pragma unroll
            for (int q = 0; q < 6; ++q)
                Ph[(i0 + r)*PSTR + jh0 + q] = pkh2(acc[r][2*q], acc[r][2*q+1]);
    }
    __syncthreads();

    // --- phase 5: Z = lrow * (U @ P~^T); U cvt'd on fly, dot2 along j ---
    const int ci = t & 15, ii = t >> 4;
    const int c0z = 4*ci, i0z = 12*ii;
    const float* Ub = U + gbase;
    float accz[4][12];
#pragma unroll
    for (int k = 0; k < 4; ++k)
#pragma unroll
        for (int m = 0; m < 12; ++m) accz[k][m] = 0.f;
    for (int jt = 0; jt < 192; jt += 8) {
        h2 uh[4][4];
#pragma unroll
        for (int k = 0; k < 4; ++k) {
            const float4 ua = *reinterpret_cast<const float4*>(&Ub[(size_t)(c0z+k)*NPIX + jt]);
            const float4 ub = *reinterpret_cast<const float4*>(&Ub[(size_t)(c0z+k)*NPIX + jt + 4]);
            uh[k][0] = pkh2(ua.x, ua.y); uh[k][1] = pkh2(ua.z, ua.w);
            uh[k][2] = pkh2(ub.x, ub.y); uh[k][3] = pkh2(ub.z, ub.w);
        }
        h2 ph[12][4];
#pragma unroll
        for (int m = 0; m < 12; ++m)
            ld4h2(&Ph[(i0z+m)*PSTR + (jt >> 1)], ph[m]);
#pragma unroll
        for (int k = 0; k < 4; ++k)
#pragma unroll
            for (int m = 0; m < 12; ++m) {
                float a = accz[k][m];
                a = dot2f(uh[k][0], ph[m][0], a);
                a = dot2f(uh[k][1], ph[m][1], a);
                a = dot2f(uh[k][2], ph[m][2], a);
                a = dot2f(uh[k][3], ph[m][3], a);
                accz[k][m] = a;
            }
    }
    float lr[12];
#pragma unroll
    for (int m = 0; m < 12; ++m) lr[m] = lrow[i0z + m];
#pragma unroll
    for (int k = 0; k < 4; ++k) {
        float* zr = Z + gbase + (size_t)(c0z + k)*NPIX + i0z;
        float4 o0, o1, o2;
        o0.x = accz[k][0]*lr[0]; o0.y = accz[k][1]*lr[1];  o0.z = accz[k][2]*lr[2];   o0.w = accz[k][3]*lr[3];
        o1.x = accz[k][4]*lr[4]; o1.y = accz[k][5]*lr[5];  o1.z = accz[k][6]*lr[6];   o1.w = accz[k][7]*lr[7];
        o2.x = accz[k][8]*lr[8]; o2.y = accz[k][9]*lr[9];  o2.z = accz[k][10]*lr[10]; o2.w = accz[k][11]*lr[11];
        *reinterpret_cast<float4*>(zr)     = o0;
        *reinterpret_cast<float4*>(zr + 4) = o1;
        *reinterpret_cast<float4*>(zr + 8) = o2;
    }
}

// ---------------------------------------------------------------------------
// HW transpose per image: out[img][x][y] = in[img][y][x]. grid (6,6,B*C).
// ---------------------------------------------------------------------------
__global__ __launch_bounds__(256) void k_transpose(
    const float* __restrict__ in, float* __restrict__ out)
{
    __shared__ float tile[32][33];
    const int tx = threadIdx.x & 31, ty = threadIdx.x >> 5;
    const int x0 = blockIdx.x*32, y0 = blockIdx.y*32;
    const float* img = in + blockIdx.z * NPIX;
    float* og = out + blockIdx.z * NPIX;
#pragma unroll
    for (int r = ty; r < 32; r += 8) tile[r][tx] = img[(y0+r)*WW + x0+tx];
    __syncthreads();
#pragma unroll
    for (int r = ty; r < 32; r += 8) og[(x0+r)*WW + (y0+tx)] = tile[tx][r];
}

// ---------------------------------------------------------------------------
// Dual transpose: z < B*C -> inA->outA, else inB->outB (one launch ramp).
// ---------------------------------------------------------------------------
__global__ __launch_bounds__(256) void k_transpose2(
    const float* __restrict__ inA, float* __restrict__ outA,
    const float* __restrict__ inB, float* __restrict__ outB)
{
    __shared__ float tile[32][33];
    const int tx = threadIdx.x & 31, ty = threadIdx.x >> 5;
    const int x0 = blockIdx.x*32, y0 = blockIdx.y*32;
    const int z = blockIdx.z;
    const float* img = (z < BB*C) ? inA + (size_t)z*NPIX
                                  : inB + (size_t)(z - BB*C)*NPIX;
    float* og = (z < BB*C) ? outA + (size_t)z*NPIX
                           : outB + (size_t)(z - BB*C)*NPIX;
#pragma unroll
    for (int r = ty; r < 32; r += 8) tile[r][tx] = img[(y0+r)*WW + x0+tx];
    __syncthreads();
#pragma unroll
    for (int r = ty; r < 32; r += 8) og[(x0+r)*WW + (y0+tx)] = tile[tx][r];
}

// ---------------------------------------------------------------------------
extern "C" void kernel_launch(void* const* d_in, const int* in_sizes, int n_in,
                              void* d_out, int out_size, void* d_ws, size_t ws_size,
                              hipStream_t stream) {
    const float* x       = (const float*)d_in[0];
    const float* pw_w    = (const float*)d_in[1];
    const float* dw_w    = (const float*)d_in[2];
    const float* dw_b    = (const float*)d_in[3];
    const float* conv2_w = (const float*)d_in[4];
    const float* conv2_b = (const float*)d_in[5];
    const float* conv0_w = (const float*)d_in[6];
    const float* conv0_b = (const float*)d_in[7];
    const float* attq    = (const float*)d_in[8];
    const float* attk    = (const float*)d_in[9];
    const float* attv    = (const float*)d_in[10];
    const float* attp    = (const float*)d_in[11];
    const float* temp    = (const float*)d_in[12];
    const float* rq      = (const float*)d_in[13];
    const float* rk      = (const float*)d_in[14];
    const float* rv      = (const float*)d_in[15];
    const float* rg      = (const float*)d_in[16];
    const float* cq      = (const float*)d_in[17];
    const float* ck      = (const float*)d_in[18];
    const float* cv      = (const float*)d_in[19];
    const float* cg      = (const float*)d_in[20];
    const float* fw      = (const float*)d_in[21];
    const float* fb      = (const float*)d_in[22];

    float* ws = (float*)d_ws;
    float* A  = ws;                 // t0 -> x1 (lives to end)
    float* Bf = ws + (size_t)ST;    // g -> out1
    float* Cf = ws + 2*(size_t)ST;  // x1t -> Z2
    float* Df = ws + 3*(size_t)ST;  // out1t -> Z3
    float* Ef = ws + 4*(size_t)ST;  // Z3t
    float* partials = ws + 5*(size_t)ST;   // 576*4096 = 2359296 floats
    float* G1 = partials + 576*4096;       // 16384
    float* M2 = G1 + 16384;                // 16384
    float* Wtr  = M2 + 16384;              // 5 x 4096
    float* Wtc  = Wtr + 4096;
    float* Wf2p = Wtc + 4096;
    float* Wf3p = Wf2p + 4096;
    float* Wfx  = Wf3p + 4096;

    const size_t need = ((size_t)5*ST + 576*4096 + 16384 + 16384 + 5*4096)
                        * sizeof(float);
    if (ws_size < need) {
        fprintf(stderr, "kernel_launch: ws_size %zu < needed %zu\n", ws_size, need);
        return;
    }

    (void)hipFuncSetAttribute((const void*)k_gram_part,
        hipFuncAttributeMaxDynamicSharedMemorySize, 69632);
    (void)hipFuncSetAttribute((const void*)k_attn_small,
        hipFuncAttributeMaxDynamicSharedMemorySize, 74240);
    (void)hipFuncSetAttribute((const void*)k_attn_fused,
        hipFuncAttributeMaxDynamicSharedMemorySize, 77568);
    (void)hipFuncSetAttribute((const void*)k_conv4,
        hipFuncAttributeMaxDynamicSharedMemorySize, 51200);
    (void)hipFuncSetAttribute((const void*)(k_gconv<false,false,false>),
        hipFuncAttributeMaxDynamicSharedMemorySize, 51200);
    (void)hipFuncSetAttribute((const void*)(k_gconv<true,false,false>),
        hipFuncAttributeMaxDynamicSharedMemorySize, 51200);
    (void)hipFuncSetAttribute((const void*)(k_gconv<false,true,false>),
        hipFuncAttributeMaxDynamicSharedMemorySize, 51200);

    const dim3 blk256(256), blk192(192);
    const dim3 gconv(NPIX/128, BB);      // (288, 4)
    const dim3 ggram(NPIX/256, BB);      // (144, 4)
    const dim3 gline(HH, BB);            // (192, 4)
    const dim3 gtr(6, 6, BB*C);
    const dim3 gtr2(6, 6, 2*BB*C);

    // 0) fold weights
    k_small_mats<<<dim3(5), blk256, 0, stream>>>(rq, rk, cq, ck, fw, rv, cv,
                                                 rg, cg, Wtr, Wtc, Wf2p, Wf3p, Wfx);
    // 1) A = pw_w @ x
    k_gconv<false,false,false><<<gconv, blk256, 51200, stream>>>(
        x, nullptr, pw_w, nullptr, nullptr, nullptr, A, 64, 64);
    // 2) B = gelu(dw3x3(A) + dw_b)
    k_dw<<<dim3(HH, BB*C), blk192, 0, stream>>>(A, dw_w, dw_b, Bf);
    // 3) A = x1 = conv2@B + conv0@x + conv2_b + conv0_b
    k_gconv<true,false,false><<<gconv, blk256, 51200, stream>>>(
        Bf, x, conv2_w, conv0_w, conv2_b, conv0_b, A, 64, 64);
    // 4) channel attention collapse -> M2
    k_gram_part<<<ggram, blk256, 69632, stream>>>(A, partials);
    k_gram_reduce<<<dim3(64), blk256, 0, stream>>>(partials, G1);
    k_attn_small<<<dim3(BB), blk256, 74240, stream>>>(G1, attq, attk, attv, attp, temp, M2);
    // 5) B = out1 = M2[b] @ x1
    k_gconv<false,true,false><<<gconv, blk256, 51200, stream>>>(
        A, nullptr, M2, nullptr, nullptr, nullptr, Bf, 64, 64);
    // 6) C = x1t, D = out1t (one dual-transpose launch)
    k_transpose2<<<gtr2, blk256, 0, stream>>>(A, Cf, Bf, Df);
    // 7) col attention fused: E = Z3t
    k_attn_fused<<<gline, blk256, 77568, stream>>>(Cf, Wtc, Df, Ef);
    // 8) D = Z3 = transpose(Z3t)
    k_transpose<<<gtr, blk256, 0, stream>>>(Ef, Df);
    // 9) row attention fused: C = Z2
    k_attn_fused<<<gline, blk256, 77568, stream>>>(A, Wtr, Bf, Cf);
    // 10) FUSED final conv: out = gelu(fw[:,0:64]@out1 + Wf2p@Z2 + Wf3p@Z3
    //                                   + Wfx@x1 + fb)
    k_conv4<<<gconv, blk256, 51200, stream>>>(
        Bf, Cf, Df, A, fw, Wf2p, Wf3p, Wfx, fb, (float*)d_out);
}